// Round 15
// baseline (1131.518 us; speedup 1.0000x reference)
//
#include <hip/hip_runtime.h>

typedef unsigned short u16;
typedef unsigned int u32;
typedef unsigned long long u64;
using bf16x8 = __attribute__((ext_vector_type(8))) short;
using f32x4  = __attribute__((ext_vector_type(4))) float;
using u32x4  = __attribute__((ext_vector_type(4))) u32;
using u32x2  = __attribute__((ext_vector_type(2))) u32;

__device__ __forceinline__ float b2f(u16 h) {
    u32 u = ((u32)h) << 16;
    float f;
    __builtin_memcpy(&f, &u, 4);
    return f;
}
__device__ __forceinline__ u16 f2b(float f) {
    u32 u;
    __builtin_memcpy(&u, &f, 4);
    u32 r = (u + 0x7fffu + ((u >> 16) & 1u)) >> 16;
    return (u16)r;
}
__device__ __forceinline__ void gload16(const u16* g, u16* l) {
    __builtin_amdgcn_global_load_lds(
        (const __attribute__((address_space(1))) u32*)g,
        (__attribute__((address_space(3))) u32*)l, 16, 0, 0);
}

// ---------------------------------------------------------------------------
// wconv: convert 10 f32 weight matrices to bf16 into one 2 MiB buffer.
// ---------------------------------------------------------------------------
struct WPack { const float* s[10]; };

__global__ __launch_bounds__(256)
void wconv_kernel(WPack p, u16* __restrict__ dst) {
    const int id = blockIdx.x * 256 + threadIdx.x;  // 0..262143
    const int e = id * 4;
    const int unit = e >> 16;  // 0..15
    const u64 arrmap = 0x9988766544332110ull;
    const u64 startmap = 0xECB9864310ull;  // start unit of arr (nibbles)
    const int arr = (int)((arrmap >> (unit * 4)) & 15);
    const int start = (int)((startmap >> (arr * 4)) & 15);
    const int off = e - (start << 16);
    f32x4 v = *(const f32x4*)(p.s[arr] + off);
    u32x2 w;
    w[0] = (u32)f2b(v[0]) | ((u32)f2b(v[1]) << 16);
    w[1] = (u32)f2b(v[2]) | ((u32)f2b(v[3]) << 16);
    *(u32x2*)(dst + e) = w;
}

// ---------------------------------------------------------------------------
// gather_raw: window-partition [4,256,128,128] f32 -> raw bf16 window layout
// [1024*64,256]. One block per PAIR of horizontally adjacent windows: reads
// are full 64B lines, writes are linear contiguous 16B chunks.
// ---------------------------------------------------------------------------
__global__ __launch_bounds__(256)
void gather_raw_kernel(const float* __restrict__ X, u16* __restrict__ raw) {
    __shared__ __align__(16) u16 win[128][264];  // [w2*64 + y*8 + x][c]
    const int tid = threadIdx.x;
    const int blk2 = blockIdx.x;  // 0..511
    const int b = blk2 >> 7, hb = (blk2 >> 3) & 15, wp = blk2 & 7;
#pragma unroll
    for (int it = 0; it < 8; ++it) {
        const int id = it * 256 + tid;
        const int c = id & 255, y = id >> 8;
        const size_t off =
            (((size_t)(b * 256 + c) * 128) + hb * 8 + y) * 128 + wp * 16;
        f32x4 v0 = *(const f32x4*)(X + off);
        f32x4 v1 = *(const f32x4*)(X + off + 4);
        f32x4 v2 = *(const f32x4*)(X + off + 8);
        f32x4 v3 = *(const f32x4*)(X + off + 12);
#pragma unroll
        for (int x = 0; x < 4; ++x) {
            win[y * 8 + x][c] = f2b(v0[x]);
            win[y * 8 + 4 + x][c] = f2b(v1[x]);
            win[64 + y * 8 + x][c] = f2b(v2[x]);
            win[64 + y * 8 + 4 + x][c] = f2b(v3[x]);
        }
    }
    __syncthreads();
    const size_t base = (size_t)((b * 16 + hb) * 16 + wp * 2) * 64 * 256;
#pragma unroll
    for (int it = 0; it < 16; ++it) {
        const int e8 = it * 256 + tid;
        const int tok = e8 >> 5, c0 = (e8 & 31) * 8;
        *(u32x4*)(raw + base + (size_t)e8 * 8) = *(const u32x4*)&win[tok][c0];
    }
}

// ---------------------------------------------------------------------------
// GEMM v8: C[M,N] = A'[M,K] @ W[N,K]^T + bias, where A' = LN(A) if LNA else A.
// Tile 64x64, 256 thr (4 waves, 32x32 quadrants).
// LNA=0: v7 path — BK=128 single-buffered, 32 KB LDS, 5 blocks/CU.
// LNA=1 (K must be 256): full-K A staged (32KB) + W BK=128 (16KB) = 48 KB,
//   3 blocks/CU. After the stage drain, each thread LN-transforms its own
//   row-quarter in LDS (thread-local chunks; swizzle is an involution).
// XCD decode: bid=(mseq*S+strip)*8+xcd -> strip-blocks sharing an A-tile
// land on one XCD. XOR-swizzled LDS both sides (rule #21).
// RES: 0=none, 1=+bf16 windowed residual. EPI: 0=none, 1=GELU(exact).
// ---------------------------------------------------------------------------
template <int K, int N, int LNA, int RES, int EPI>
__global__ __launch_bounds__(256)
void gemm_kernel(const u16* __restrict__ A, const u16* __restrict__ Wt,
                 const float* __restrict__ bias, const float* __restrict__ lng,
                 const float* __restrict__ lnb, const u16* __restrict__ resw,
                 u16* __restrict__ Cout) {
    static_assert(!LNA || K == 256, "LN fusion requires K=256");
    constexpr int S = N / 64;          // N-strips
    constexpr int AK = LNA ? 256 : 128;
    __shared__ __align__(16) u16 As[64][AK];
    __shared__ __align__(16) u16 Bs[64][128];
    const int tid = threadIdx.x;
    const int lane = tid & 63, w = tid >> 6;
    const int cl = lane & 15, g = lane >> 4;
    const int wr = w >> 1, wc = w & 1;
    const int bid = blockIdx.x;
    const int xcd = bid & 7, rest = bid >> 3;
    const int strip = rest % S, mseq = rest / S;
    const int m0 = (xcd * 128 + mseq) * 64;
    const int n0 = strip * 64;
    f32x4 acc[2][2] = {};

    if constexpr (LNA) {
        // ---- stage full-K A (8 instr/wave) + W phase 0 (4 instr/wave) ----
        {
            const int row2 = lane >> 5, sc32 = lane & 31;
#pragma unroll
            for (int it = 0; it < 8; ++it) {
                const int rp = w * 16 + it * 2;
                const int row = rp + row2;
                const int ch = (sc32 & 24) | ((sc32 ^ row) & 7);
                gload16(&A[(size_t)(m0 + row) * K + ch * 8], &As[rp][0]);
            }
            const int row4 = lane >> 4, sc16 = lane & 15;
#pragma unroll
            for (int it = 0; it < 4; ++it) {
                const int rp = w * 16 + it * 4;
                const int row = rp + row4;
                const int ch = (sc16 & 8) | ((sc16 ^ row) & 7);
                gload16(&Wt[(size_t)(n0 + row) * K + ch * 8], &Bs[rp][0]);
            }
        }
        asm volatile("s_waitcnt vmcnt(0)" ::: "memory");
        __syncthreads();
        // ---- LN in-place: thread owns quarter-row of row tok ----
        {
            const int tok = tid >> 2, qd = tid & 3;
            u32x4 cv[8];
            float s = 0.f, s2 = 0.f;
#pragma unroll
            for (int i = 0; i < 8; ++i) {
                const int ch = qd * 8 + i;
                const int a = (ch & 24) | ((ch ^ tok) & 7);
                cv[i] = *(const u32x4*)&As[tok][a * 8];
                const u16* pv = (const u16*)&cv[i];
#pragma unroll
                for (int x = 0; x < 8; ++x) {
                    float v = b2f(pv[x]);
                    s += v;
                    s2 += v * v;
                }
            }
            s += __shfl_xor(s, 1);  s += __shfl_xor(s, 2);
            s2 += __shfl_xor(s2, 1); s2 += __shfl_xor(s2, 2);
            const float mean = s * (1.f / 256.f);
            const float var = s2 * (1.f / 256.f) - mean * mean;
            const float rstd = rsqrtf(var + 1e-5f);
#pragma unroll
            for (int i = 0; i < 8; ++i) {
                const int ch = qd * 8 + i;
                const int a = (ch & 24) | ((ch ^ tok) & 7);
                const u16* pv = (const u16*)&cv[i];
                f32x4 g0 = *(const f32x4*)&lng[ch * 8];
                f32x4 g1 = *(const f32x4*)&lng[ch * 8 + 4];
                f32x4 t0 = *(const f32x4*)&lnb[ch * 8];
                f32x4 t1 = *(const f32x4*)&lnb[ch * 8 + 4];
                __align__(16) u16 ov[8];
#pragma unroll
                for (int x = 0; x < 4; ++x) {
                    ov[x] = f2b((b2f(pv[x]) - mean) * rstd * g0[x] + t0[x]);
                    ov[4 + x] =
                        f2b((b2f(pv[4 + x]) - mean) * rstd * g1[x] + t1[x]);
                }
                *(u32x4*)&As[tok][a * 8] = *(u32x4*)ov;
            }
        }
        __syncthreads();
        // ---- 2 W-phases of MFMA ----
#pragma unroll
        for (int ph = 0; ph < 2; ++ph) {
            if (ph) {
                __syncthreads();  // all Bs reads of ph0 done
                const int row4 = lane >> 4, sc16 = lane & 15;
#pragma unroll
                for (int it = 0; it < 4; ++it) {
                    const int rp = w * 16 + it * 4;
                    const int row = rp + row4;
                    const int ch = (sc16 & 8) | ((sc16 ^ row) & 7);
                    gload16(&Wt[(size_t)(n0 + row) * K + 128 + ch * 8],
                            &Bs[rp][0]);
                }
                asm volatile("s_waitcnt vmcnt(0)" ::: "memory");
                __syncthreads();
            }
#pragma unroll
            for (int ks = 0; ks < 4; ++ks) {
                const int J16 = ks * 4 + g;       // W chunk 0..15
                const int JA = ph * 16 + J16;     // A chunk 0..31
                bf16x8 af[2], bw[2];
#pragma unroll
                for (int i = 0; i < 2; ++i) {
                    const int r = wr * 32 + i * 16 + cl;
                    af[i] = *(const bf16x8*)
                        &As[r][(((JA & 24) | ((JA ^ r) & 7))) * 8];
                }
#pragma unroll
                for (int j = 0; j < 2; ++j) {
                    const int r = wc * 32 + j * 16 + cl;
                    bw[j] = *(const bf16x8*)
                        &Bs[r][(((J16 & 8) | ((J16 ^ r) & 7))) * 8];
                }
#pragma unroll
                for (int i = 0; i < 2; ++i)
#pragma unroll
                    for (int j = 0; j < 2; ++j)
                        acc[i][j] = __builtin_amdgcn_mfma_f32_16x16x32_bf16(
                            af[i], bw[j], acc[i][j], 0, 0, 0);
            }
        }
    } else {
        constexpr int NPH = K / 128;
        const int srow = lane >> 4, sch = lane & 15;
#pragma unroll
        for (int ph = 0; ph < NPH; ++ph) {
            if (ph) __syncthreads();
#pragma unroll
            for (int it = 0; it < 4; ++it) {
                const int rp = w * 16 + it * 4;
                const int row = rp + srow;
                const int ch = (sch & 8) | ((sch ^ row) & 7);
                gload16(&A[(size_t)(m0 + row) * K + ph * 128 + ch * 8],
                        &As[rp][0]);
                gload16(&Wt[(size_t)(n0 + row) * K + ph * 128 + ch * 8],
                        &Bs[rp][0]);
            }
            asm volatile("s_waitcnt vmcnt(0)" ::: "memory");
            __syncthreads();
#pragma unroll
            for (int ks = 0; ks < 4; ++ks) {
                const int J = ks * 4 + g;
                bf16x8 af[2], bw[2];
#pragma unroll
                for (int i = 0; i < 2; ++i) {
                    const int r = wr * 32 + i * 16 + cl;
                    af[i] = *(const bf16x8*)
                        &As[r][(((J & 8) | ((J ^ r) & 7))) * 8];
                }
#pragma unroll
                for (int j = 0; j < 2; ++j) {
                    const int r = wc * 32 + j * 16 + cl;
                    bw[j] = *(const bf16x8*)
                        &Bs[r][(((J & 8) | ((J ^ r) & 7))) * 8];
                }
#pragma unroll
                for (int i = 0; i < 2; ++i)
#pragma unroll
                    for (int j = 0; j < 2; ++j)
                        acc[i][j] = __builtin_amdgcn_mfma_f32_16x16x32_bf16(
                            af[i], bw[j], acc[i][j], 0, 0, 0);
            }
        }
    }
    // ---- epilogue: acc -> LDS (reuse As) -> coalesced 16B stores ----
    __syncthreads();
    u16 (*Cs)[72] = (u16(*)[72])&As[0][0];
#pragma unroll
    for (int i = 0; i < 2; ++i)
#pragma unroll
        for (int j = 0; j < 2; ++j)
#pragma unroll
            for (int rr = 0; rr < 4; ++rr)
                Cs[wr * 32 + i * 16 + g * 4 + rr][wc * 32 + j * 16 + cl] =
                    f2b(acc[i][j][rr]);
    __syncthreads();
#pragma unroll
    for (int it = 0; it < 2; ++it) {
        const int idx = it * 256 + tid;
        const int row = idx >> 3, ch = idx & 7;
        const int grow = m0 + row, gcol = n0 + ch * 8;
        u32x4 cv = *(const u32x4*)&Cs[row][ch * 8];
        const u16* pc = (const u16*)&cv;
        f32x4 b0 = *(const f32x4*)&bias[gcol];
        f32x4 b1 = *(const f32x4*)&bias[gcol + 4];
        float v[8];
#pragma unroll
        for (int x = 0; x < 4; ++x) {
            v[x] = b2f(pc[x]) + b0[x];
            v[4 + x] = b2f(pc[4 + x]) + b1[x];
        }
        if constexpr (RES == 1) {
            u32x4 rv = *(const u32x4*)&resw[(size_t)grow * N + gcol];
            const u16* pr = (const u16*)&rv;
#pragma unroll
            for (int x = 0; x < 8; ++x) v[x] += b2f(pr[x]);
        }
        if constexpr (EPI == 1)
#pragma unroll
            for (int x = 0; x < 8; ++x)
                v[x] = 0.5f * v[x] * (1.f + erff(v[x] * 0.70710678118654752f));
        u32x4 ov;
#pragma unroll
        for (int x = 0; x < 4; ++x)
            ov[x] = (u32)f2b(v[2 * x]) | ((u32)f2b(v[2 * x + 1]) << 16);
        *(u32x4*)&Cout[(size_t)grow * N + gcol] = ov;
    }
}

// ---------------------------------------------------------------------------
// MFMA attention. One wave per (window, head). Grid 2048 x 256thr (4 waves).
// ---------------------------------------------------------------------------
__global__ __launch_bounds__(256)
void attn_mfma_kernel(const u16* __restrict__ Q, const u16* __restrict__ KV,
                      const float* __restrict__ rpb, u16* __restrict__ O) {
    __shared__ __align__(16) u16 Pq[4][64][72];
    __shared__ __align__(16) u16 Vt[4][32][72];
    __shared__ float rb[4][228];
    const int w = threadIdx.x >> 6, lane = threadIdx.x & 63;
    const int gw = blockIdx.x * 4 + w;
    const int win = gw >> 3, h = gw & 7;
    const int c = lane & 15, g = lane >> 4;
    for (int i = lane; i < 225; i += 64) rb[w][i] = rpb[i * 8 + h];
    {
        const u16* Vrow = KV + ((size_t)(win * 64 + lane)) * 512 + 256 + h * 32;
        u32x4 vv[4];
#pragma unroll
        for (int ch = 0; ch < 4; ++ch) vv[ch] = *(const u32x4*)(Vrow + ch * 8);
        const u16* pv = (const u16*)vv;
#pragma unroll
        for (int d = 0; d < 32; ++d) Vt[w][d][lane] = pv[d];
    }
    const u16* Qb = Q + ((size_t)win * 64 + c) * 256 + h * 32 + g * 8;
    const u16* Kb = KV + ((size_t)win * 64 + c) * 512 + h * 32 + g * 8;
    bf16x8 qf[4], kf[4];
#pragma unroll
    for (int t = 0; t < 4; ++t) {
        qf[t] = *(const bf16x8*)(Qb + (size_t)t * 16 * 256);
        kf[t] = *(const bf16x8*)(Kb + (size_t)t * 16 * 512);
    }
    f32x4 st[4][4];
#pragma unroll
    for (int kb = 0; kb < 4; ++kb)
#pragma unroll
        for (int qb = 0; qb < 4; ++qb) {
            f32x4 z = {0.f, 0.f, 0.f, 0.f};
            st[kb][qb] = __builtin_amdgcn_mfma_f32_16x16x32_bf16(kf[kb], qf[qb], z, 0, 0, 0);
        }
    __syncthreads();
    const float scale = 0.17677669529663687f;
    const int qy2 = c >> 3, qx = c & 7;
#pragma unroll
    for (int qb = 0; qb < 4; ++qb) {
        float sv[16];
#pragma unroll
        for (int kb = 0; kb < 4; ++kb)
#pragma unroll
            for (int r = 0; r < 4; ++r) {
                const int k = kb * 16 + 4 * g + r;
                const int dy = (qb * 2 + qy2) - (k >> 3) + 7;
                const int dx = qx - (k & 7) + 7;
                sv[kb * 4 + r] = st[kb][qb][r] * scale + rb[w][dy * 15 + dx];
            }
        float mx = sv[0];
#pragma unroll
        for (int j = 1; j < 16; ++j) mx = fmaxf(mx, sv[j]);
        mx = fmaxf(mx, __shfl_xor(mx, 16));
        mx = fmaxf(mx, __shfl_xor(mx, 32));
        float sum = 0.f;
#pragma unroll
        for (int j = 0; j < 16; ++j) {
            sv[j] = __expf(sv[j] - mx);
            sum += sv[j];
        }
        sum += __shfl_xor(sum, 16);
        sum += __shfl_xor(sum, 32);
        const float inv = 1.f / sum;
#pragma unroll
        for (int kb = 0; kb < 4; ++kb) {
            u32x2 pk;
            pk[0] = (u32)f2b(sv[kb * 4 + 0] * inv) | ((u32)f2b(sv[kb * 4 + 1] * inv) << 16);
            pk[1] = (u32)f2b(sv[kb * 4 + 2] * inv) | ((u32)f2b(sv[kb * 4 + 3] * inv) << 16);
            *(u32x2*)&Pq[w][qb * 16 + c][kb * 16 + 4 * g] = pk;
        }
    }
    __syncthreads();
    f32x4 ot[4][2] = {};
#pragma unroll
    for (int ks = 0; ks < 2; ++ks) {
        bf16x8 bfr[2];
#pragma unroll
        for (int db = 0; db < 2; ++db)
            bfr[db] = *(const bf16x8*)&Vt[w][db * 16 + c][ks * 32 + g * 8];
#pragma unroll
        for (int qb = 0; qb < 4; ++qb) {
            bf16x8 af = *(const bf16x8*)&Pq[w][qb * 16 + c][ks * 32 + g * 8];
#pragma unroll
            for (int db = 0; db < 2; ++db)
                ot[qb][db] = __builtin_amdgcn_mfma_f32_16x16x32_bf16(af, bfr[db], ot[qb][db], 0, 0, 0);
        }
    }
    u16* Ob = O + ((size_t)win * 64) * 256 + h * 32;
#pragma unroll
    for (int qb = 0; qb < 4; ++qb)
#pragma unroll
        for (int db = 0; db < 2; ++db)
#pragma unroll
            for (int r = 0; r < 4; ++r)
                Ob[(size_t)(qb * 16 + 4 * g + r) * 256 + db * 16 + c] = f2b(ot[qb][db][r]);
}

// ---------------------------------------------------------------------------
// scatter v2: window layout [1024*64,256] bf16 -> [4,256,128,128] f32.
// ---------------------------------------------------------------------------
__global__ __launch_bounds__(256)
void scatter_kernel(const u16* __restrict__ Wn, float* __restrict__ out) {
    __shared__ __align__(16) u16 win[128][264];
    const int tid = threadIdx.x;
    const int blk2 = blockIdx.x;  // 0..511
    const int b = blk2 >> 7, hb = (blk2 >> 3) & 15, wp = blk2 & 7;
    const size_t base = (size_t)((b * 16 + hb) * 16 + wp * 2) * 64 * 256;
#pragma unroll
    for (int it = 0; it < 16; ++it) {
        const int e8 = it * 256 + tid;
        const int tok = e8 >> 5, c0 = (e8 & 31) * 8;
        *(u32x4*)&win[tok][c0] = *(const u32x4*)(Wn + base + (size_t)e8 * 8);
    }
    __syncthreads();
#pragma unroll
    for (int it = 0; it < 8; ++it) {
        const int id = it * 256 + tid;
        const int c = id & 255, y = id >> 8;
        f32x4 o0, o1, o2, o3;
#pragma unroll
        for (int x = 0; x < 4; ++x) {
            o0[x] = b2f(win[y * 8 + x][c]);
            o1[x] = b2f(win[y * 8 + 4 + x][c]);
            o2[x] = b2f(win[64 + y * 8 + x][c]);
            o3[x] = b2f(win[64 + y * 8 + 4 + x][c]);
        }
        const size_t oo =
            (((size_t)(b * 256 + c) * 128) + hb * 8 + y) * 128 + wp * 16;
        *(f32x4*)(out + oo) = o0;
        *(f32x4*)(out + oo + 4) = o1;
        *(f32x4*)(out + oo + 8) = o2;
        *(f32x4*)(out + oo + 12) = o3;
    }
}

// ---------------------------------------------------------------------------
extern "C" void kernel_launch(void* const* d_in, const int* in_sizes, int n_in,
                              void* d_out, int out_size, void* d_ws,
                              size_t ws_size, hipStream_t stream) {
    const float* spatial = (const float*)d_in[0];
    const float* freq    = (const float*)d_in[1];
    const float* s_qw  = (const float*)d_in[2];
    const float* s_qb  = (const float*)d_in[3];
    const float* s_kvw = (const float*)d_in[4];
    const float* s_kvb = (const float*)d_in[5];
    const float* s_rpb = (const float*)d_in[6];
    const float* s_pw  = (const float*)d_in[7];
    const float* s_pb  = (const float*)d_in[8];
    const float* f_qw  = (const float*)d_in[9];
    const float* f_qb  = (const float*)d_in[10];
    const float* f_kvw = (const float*)d_in[11];
    const float* f_kvb = (const float*)d_in[12];
    const float* f_rpb = (const float*)d_in[13];
    const float* f_pw  = (const float*)d_in[14];
    const float* f_pb  = (const float*)d_in[15];
    const float* ns1_g = (const float*)d_in[16];
    const float* ns1_b = (const float*)d_in[17];
    const float* nfs_g = (const float*)d_in[18];
    const float* nfs_b = (const float*)d_in[19];
    const float* ns2_g = (const float*)d_in[20];
    const float* ns2_b = (const float*)d_in[21];
    const float* nf1_g = (const float*)d_in[22];
    const float* nf1_b = (const float*)d_in[23];
    const float* nsf_g = (const float*)d_in[24];
    const float* nsf_b = (const float*)d_in[25];
    const float* nf2_g = (const float*)d_in[26];
    const float* nf2_b = (const float*)d_in[27];
    const float* ffns_w1 = (const float*)d_in[28];
    const float* ffns_b1 = (const float*)d_in[29];
    const float* ffns_w2 = (const float*)d_in[30];
    const float* ffns_b2 = (const float*)d_in[31];
    const float* ffnf_w1 = (const float*)d_in[32];
    const float* ffnf_b1 = (const float*)d_in[33];
    const float* ffnf_w2 = (const float*)d_in[34];
    const float* ffnf_b2 = (const float*)d_in[35];

    float* out = (float*)d_out;
    char* ob = (char*)d_out;
    char* ws = (char*)d_ws;
    const size_t MB32 = (size_t)32 << 20;
    u16* U0  = (u16*)ob;               // 32 MiB (attn out)
    u16* U1  = (u16*)(ob + MB32);      // 32 MiB (q / s1)
    u16* U23 = (u16*)(ob + 2 * MB32);  // 64 MiB (kv / hid)
    u16* W0  = (u16*)ws;               // 32 MiB (s2, then f2)
    u16* W1  = (u16*)(ws + MB32);      // 32 MiB (f1)
    u16* WB  = (u16*)(ws + 2 * MB32);  // 2 MiB bf16 weights
    u16* R0  = (u16*)(ws + 2 * MB32 + (2 << 20));           // raw spatial win
    u16* R1  = (u16*)(ws + 2 * MB32 + (2 << 20) + MB32);    // raw freq win

    // unit layout (64Ki elems each), per wconv startmap 0xECB9864310:
    // 0:s_qw  1-2:s_kvw  3:s_pw  4-5:ffns_w1  6-7:ffns_w2
    // 8:f_qw  9-10:f_kvw 11:f_pw 12-13:ffnf_w1 14-15:ffnf_w2
    const u16* w_sq  = WB;
    const u16* w_skv = WB + 1 * 65536;
    const u16* w_sp  = WB + 3 * 65536;
    const u16* w_sw1 = WB + 4 * 65536;
    const u16* w_sw2 = WB + 6 * 65536;
    const u16* w_fq  = WB + 8 * 65536;
    const u16* w_fkv = WB + 9 * 65536;
    const u16* w_fp  = WB + 11 * 65536;
    const u16* w_fw1 = WB + 12 * 65536;
    const u16* w_fw2 = WB + 14 * 65536;

    WPack wp;
    wp.s[0] = s_qw;  wp.s[1] = s_kvw; wp.s[2] = s_pw;  wp.s[3] = ffns_w1;
    wp.s[4] = ffns_w2; wp.s[5] = f_qw; wp.s[6] = f_kvw; wp.s[7] = f_pw;
    wp.s[8] = ffnf_w1; wp.s[9] = ffnf_w2;

    const dim3 B(256);
    wconv_kernel<<<1024, B, 0, stream>>>(wp, WB);
    gather_raw_kernel<<<512, B, 0, stream>>>(spatial, R0);
    gather_raw_kernel<<<512, B, 0, stream>>>(freq, R1);
    // --- direction 1: spatial queries attend frequency kv ---
    gemm_kernel<256, 512, 1, 0, 0><<<8192, B, 0, stream>>>(
        R1, w_skv, s_kvb, nfs_g, nfs_b, nullptr, U23);  // kv = LN_nfs(f)@kvw
    gemm_kernel<256, 256, 1, 0, 0><<<4096, B, 0, stream>>>(
        R0, w_sq, s_qb, ns1_g, ns1_b, nullptr, U1);     // q = LN_ns1(s)@qw
    attn_mfma_kernel<<<2048, B, 0, stream>>>(U1, U23, s_rpb, U0);
    gemm_kernel<256, 256, 0, 1, 0><<<4096, B, 0, stream>>>(
        U0, w_sp, s_pb, nullptr, nullptr, R0, U1);      // s1 = raw + proj
    gemm_kernel<256, 512, 1, 0, 1><<<8192, B, 0, stream>>>(
        U1, w_sw1, ffns_b1, ns2_g, ns2_b, nullptr, U23);  // hid = GELU(LN@w1)
    gemm_kernel<512, 256, 0, 1, 0><<<4096, B, 0, stream>>>(
        U23, w_sw2, ffns_b2, nullptr, nullptr, U1, W0);   // s2 = s1 + mlp
    // --- direction 2: frequency queries attend updated spatial kv ---
    gemm_kernel<256, 512, 1, 0, 0><<<8192, B, 0, stream>>>(
        W0, w_fkv, f_kvb, nsf_g, nsf_b, nullptr, U23);  // kv2 = LN_nsf(s2)@kvw
    gemm_kernel<256, 256, 1, 0, 0><<<4096, B, 0, stream>>>(
        R1, w_fq, f_qb, nf1_g, nf1_b, nullptr, U1);     // q2 = LN_nf1(f)@qw
    attn_mfma_kernel<<<2048, B, 0, stream>>>(U1, U23, f_rpb, U0);
    gemm_kernel<256, 256, 0, 1, 0><<<4096, B, 0, stream>>>(
        U0, w_fp, f_pb, nullptr, nullptr, R1, W1);      // f1 = raw + proj
    gemm_kernel<256, 512, 1, 0, 1><<<8192, B, 0, stream>>>(
        W1, w_fw1, ffnf_b1, nf2_g, nf2_b, nullptr, U23);  // hid2
    scatter_kernel<<<512, B, 0, stream>>>(W0, out);       // spatial_out
    gemm_kernel<512, 256, 0, 1, 0><<<4096, B, 0, stream>>>(
        U23, w_fw2, ffnf_b2, nullptr, nullptr, W1, W0);   // f2 = f1 + mlp
    scatter_kernel<<<512, B, 0, stream>>>(W0, out + 16777216);  // freq_out
}

// Round 17
// 583.988 us; speedup vs baseline: 1.9376x; 1.9376x over previous
//
#include <hip/hip_runtime.h>

typedef unsigned short u16;
typedef unsigned int u32;
typedef unsigned long long u64;
using bf16x8 = __attribute__((ext_vector_type(8))) short;
using f32x4  = __attribute__((ext_vector_type(4))) float;
using u32x4  = __attribute__((ext_vector_type(4))) u32;
using u32x2  = __attribute__((ext_vector_type(2))) u32;

__device__ __forceinline__ float b2f(u16 h) {
    u32 u = ((u32)h) << 16;
    float f;
    __builtin_memcpy(&f, &u, 4);
    return f;
}
__device__ __forceinline__ u16 f2b(float f) {
    u32 u;
    __builtin_memcpy(&u, &f, 4);
    u32 r = (u + 0x7fffu + ((u >> 16) & 1u)) >> 16;
    return (u16)r;
}
__device__ __forceinline__ void gload16(const u16* g, u16* l) {
    __builtin_amdgcn_global_load_lds(
        (const __attribute__((address_space(1))) u32*)g,
        (__attribute__((address_space(3))) u32*)l, 16, 0, 0);
}
// Barrier with compile-time fences on BOTH sides: s_barrier is not a
// compiler memory fence; without the trailing fence hipcc can hoist
// global_load_lds/ds ops across it (round-16 race, rule #18 family).
__device__ __forceinline__ void hard_barrier() {
    asm volatile("" ::: "memory");
    __builtin_amdgcn_sched_barrier(0);
    __builtin_amdgcn_s_barrier();
    __builtin_amdgcn_sched_barrier(0);
    asm volatile("" ::: "memory");
}

// ---------------------------------------------------------------------------
// wconv: convert 10 f32 weight matrices to bf16 into one 2 MiB buffer.
// ---------------------------------------------------------------------------
struct WPack { const float* s[10]; };

__global__ __launch_bounds__(256)
void wconv_kernel(WPack p, u16* __restrict__ dst) {
    const int id = blockIdx.x * 256 + threadIdx.x;  // 0..262143
    const int e = id * 4;
    const int unit = e >> 16;  // 0..15
    const u64 arrmap = 0x9988766544332110ull;
    const u64 startmap = 0xECB9864310ull;  // start unit of arr (nibbles)
    const int arr = (int)((arrmap >> (unit * 4)) & 15);
    const int start = (int)((startmap >> (arr * 4)) & 15);
    const int off = e - (start << 16);
    f32x4 v = *(const f32x4*)(p.s[arr] + off);
    u32x2 w;
    w[0] = (u32)f2b(v[0]) | ((u32)f2b(v[1]) << 16);
    w[1] = (u32)f2b(v[2]) | ((u32)f2b(v[3]) << 16);
    *(u32x2*)(dst + e) = w;
}

// ---------------------------------------------------------------------------
// gather_ln v2: window-partition [4,256,128,128] f32 -> LN'd bf16 window
// layout [1024*64,256] (+ optional raw copy). One block per PAIR of
// horizontally adjacent windows: full-64B-line reads, linear 16B writes.
// ---------------------------------------------------------------------------
__global__ __launch_bounds__(256)
void gather_ln_kernel(const float* __restrict__ X, const float* __restrict__ g,
                      const float* __restrict__ bta, u16* __restrict__ lno,
                      u16* __restrict__ raw) {
    __shared__ __align__(16) u16 win[128][264];  // [w2*64 + y*8 + x][c]
    __shared__ float mrs[128][2];
    const int tid = threadIdx.x;
    const int blk2 = blockIdx.x;  // 0..511
    const int b = blk2 >> 7, hb = (blk2 >> 3) & 15, wp = blk2 & 7;
#pragma unroll
    for (int it = 0; it < 8; ++it) {
        const int id = it * 256 + tid;
        const int c = id & 255, y = id >> 8;
        const size_t off =
            (((size_t)(b * 256 + c) * 128) + hb * 8 + y) * 128 + wp * 16;
        f32x4 v0 = *(const f32x4*)(X + off);
        f32x4 v1 = *(const f32x4*)(X + off + 4);
        f32x4 v2 = *(const f32x4*)(X + off + 8);
        f32x4 v3 = *(const f32x4*)(X + off + 12);
#pragma unroll
        for (int x = 0; x < 4; ++x) {
            win[y * 8 + x][c] = f2b(v0[x]);
            win[y * 8 + 4 + x][c] = f2b(v1[x]);
            win[64 + y * 8 + x][c] = f2b(v2[x]);
            win[64 + y * 8 + 4 + x][c] = f2b(v3[x]);
        }
    }
    __syncthreads();
    {
        const int tok = tid >> 1, half = tid & 1;
        float s = 0.f, s2 = 0.f;
#pragma unroll
        for (int i = 0; i < 16; ++i) {
            u32x4 rv = *(const u32x4*)&win[tok][half * 128 + i * 8];
            const u16* pv = (const u16*)&rv;
#pragma unroll
            for (int x = 0; x < 8; ++x) {
                float v = b2f(pv[x]);
                s += v;
                s2 += v * v;
            }
        }
        s += __shfl_xor(s, 1);
        s2 += __shfl_xor(s2, 1);
        const float mean = s * (1.f / 256.f);
        const float var = s2 * (1.f / 256.f) - mean * mean;
        if (!half) {
            mrs[tok][0] = mean;
            mrs[tok][1] = rsqrtf(var + 1e-5f);
        }
    }
    __syncthreads();
    const size_t base = (size_t)((b * 16 + hb) * 16 + wp * 2) * 64 * 256;
#pragma unroll
    for (int it = 0; it < 16; ++it) {
        const int e8 = it * 256 + tid;          // chunk id 0..4095
        const int tok = e8 >> 5, c0 = (e8 & 31) * 8;
        u32x4 rv = *(const u32x4*)&win[tok][c0];
        if (raw) *(u32x4*)(raw + base + (size_t)e8 * 8) = rv;
        const u16* pv = (const u16*)&rv;
        const float mean = mrs[tok][0], rstd = mrs[tok][1];
        f32x4 g0 = *(const f32x4*)&g[c0];
        f32x4 g1 = *(const f32x4*)&g[c0 + 4];
        f32x4 t0 = *(const f32x4*)&bta[c0];
        f32x4 t1 = *(const f32x4*)&bta[c0 + 4];
        __align__(16) u16 outv[8];
#pragma unroll
        for (int x = 0; x < 4; ++x) {
            outv[x] = f2b((b2f(pv[x]) - mean) * rstd * g0[x] + t0[x]);
            outv[4 + x] = f2b((b2f(pv[4 + x]) - mean) * rstd * g1[x] + t1[x]);
        }
        *(u32x4*)(lno + base + (size_t)e8 * 8) = *(u32x4*)outv;
    }
}

// ---------------------------------------------------------------------------
// ln: LayerNorm over last dim (256) of [65536,256] bf16 -> bf16.
// ---------------------------------------------------------------------------
__global__ __launch_bounds__(256)
void ln_kernel(const u16* __restrict__ X, const float* __restrict__ g,
               const float* __restrict__ bta, u16* __restrict__ Y) {
    const int wave = threadIdx.x >> 6, lane = threadIdx.x & 63;
    const size_t tok = (size_t)blockIdx.x * 4 + wave;
    const u16* x = X + tok * 256 + lane * 4;
    u32x2 v = *(const u32x2*)x;
    float f0 = b2f((u16)(v[0] & 0xffff)), f1 = b2f((u16)(v[0] >> 16));
    float f2v = b2f((u16)(v[1] & 0xffff)), f3 = b2f((u16)(v[1] >> 16));
    float s = f0 + f1 + f2v + f3;
    float s2 = f0 * f0 + f1 * f1 + f2v * f2v + f3 * f3;
#pragma unroll
    for (int off = 32; off; off >>= 1) {
        s += __shfl_xor(s, off);
        s2 += __shfl_xor(s2, off);
    }
    const float mean = s * (1.f / 256.f);
    const float var = s2 * (1.f / 256.f) - mean * mean;
    const float rstd = rsqrtf(var + 1e-5f);
    const int c = lane * 4;
    float o0 = (f0 - mean) * rstd * g[c + 0] + bta[c + 0];
    float o1 = (f1 - mean) * rstd * g[c + 1] + bta[c + 1];
    float o2 = (f2v - mean) * rstd * g[c + 2] + bta[c + 2];
    float o3 = (f3 - mean) * rstd * g[c + 3] + bta[c + 3];
    u32 w0 = (u32)f2b(o0) | ((u32)f2b(o1) << 16);
    u32 w1 = (u32)f2b(o2) | ((u32)f2b(o3) << 16);
    u32x2 w;
    w[0] = w0; w[1] = w1;
    *(u32x2*)(Y + tok * 256 + lane * 4) = w;
}

// ---------------------------------------------------------------------------
// GEMM v7.6: C[M,N] = A[M,K] @ W[N,K]^T + bias. Tile 64x64, 256 thr
// (4 waves, 32x32 quadrants). BK=64 DOUBLE-buffered (32 KB LDS, 5 blk/CU)
// with counted vmcnt(4). All s_barriers are hard_barrier() (fenced both
// sides) so stage/ds ops cannot be moved across them by the compiler.
// XCD decode: bid=(mseq*S+strip)*8+xcd. XOR-swizzled LDS (rule #21).
// RES: 0=none, 1=+bf16 windowed residual. EPI: 0=none, 1=GELU(exact).
// ---------------------------------------------------------------------------
template <int K, int N, int RES, int EPI>
__global__ __launch_bounds__(256)
void gemm_kernel(const u16* __restrict__ A, const u16* __restrict__ Wt,
                 const float* __restrict__ bias, const u16* __restrict__ resw,
                 u16* __restrict__ Cout) {
    constexpr int S = N / 64;    // N-strips
    constexpr int NPH = K / 64;  // phases (4 or 8)
    __shared__ __align__(16) u16 As[2][64 * 64];
    __shared__ __align__(16) u16 Bs[2][64 * 64];
    const int tid = threadIdx.x;
    const int lane = tid & 63, w = tid >> 6;
    const int cl = lane & 15, g = lane >> 4;
    const int wr = w >> 1, wc = w & 1;
    const int bid = blockIdx.x;
    const int xcd = bid & 7, rest = bid >> 3;
    const int strip = rest % S, mseq = rest / S;
    const int m0 = (xcd * 128 + mseq) * 64;  // M-tile (1024 total)
    const int n0 = strip * 64;
    const int rowg = lane >> 3;   // row within staged 8-row group
    const int sch = lane & 7;     // 16B chunk within 128B row
    f32x4 acc[2][2] = {};

    auto stage = [&](int c) {
        const int buf = c & 1;
#pragma unroll
        for (int it = 0; it < 2; ++it) {
            const int rp = w * 16 + it * 8;
            const int row = rp + rowg;
            const int ch = sch ^ (row & 7);  // pre-swizzled source chunk
            gload16(&A[(size_t)(m0 + row) * K + c * 64 + ch * 8],
                    &As[buf][rp * 64]);
            gload16(&Wt[(size_t)(n0 + row) * K + c * 64 + ch * 8],
                    &Bs[buf][rp * 64]);
        }
    };
    stage(0);
    stage(1);
#pragma unroll
    for (int c = 0; c < NPH; ++c) {
        if (c + 1 < NPH)
            asm volatile("s_waitcnt vmcnt(4)" ::: "memory");  // stage(c) done
        else
            asm volatile("s_waitcnt vmcnt(0)" ::: "memory");
        hard_barrier();
        const u16* Ab = &As[c & 1][0];
        const u16* Bb = &Bs[c & 1][0];
#pragma unroll
        for (int ks = 0; ks < 2; ++ks) {
            const int J = ks * 4 + g;  // 16B chunk of row (0..7)
            bf16x8 af[2], bw[2];
#pragma unroll
            for (int i = 0; i < 2; ++i) {
                const int r = wr * 32 + i * 16 + cl;
                af[i] = *(const bf16x8*)(Ab + r * 64 + (J ^ (r & 7)) * 8);
            }
#pragma unroll
            for (int j = 0; j < 2; ++j) {
                const int r = wc * 32 + j * 16 + cl;
                bw[j] = *(const bf16x8*)(Bb + r * 64 + (J ^ (r & 7)) * 8);
            }
#pragma unroll
            for (int i = 0; i < 2; ++i)
#pragma unroll
                for (int j = 0; j < 2; ++j)
                    acc[i][j] = __builtin_amdgcn_mfma_f32_16x16x32_bf16(
                        af[i], bw[j], acc[i][j], 0, 0, 0);
        }
        // all LDS reads of buf must complete before restage overwrites it
        asm volatile("s_waitcnt lgkmcnt(0)" ::: "memory");
        hard_barrier();
        if (c + 2 < NPH) stage(c + 2);
    }
    // ---- epilogue: acc -> LDS (reuse As) -> coalesced 16B stores ----
    u16 (*Cs)[72] = (u16(*)[72])&As[0][0];
#pragma unroll
    for (int i = 0; i < 2; ++i)
#pragma unroll
        for (int j = 0; j < 2; ++j)
#pragma unroll
            for (int rr = 0; rr < 4; ++rr)
                Cs[wr * 32 + i * 16 + g * 4 + rr][wc * 32 + j * 16 + cl] =
                    f2b(acc[i][j][rr]);
    __syncthreads();
#pragma unroll
    for (int it = 0; it < 2; ++it) {
        const int idx = it * 256 + tid;
        const int row = idx >> 3, ch = idx & 7;
        const int grow = m0 + row, gcol = n0 + ch * 8;
        u32x4 cv = *(const u32x4*)&Cs[row][ch * 8];
        const u16* pc = (const u16*)&cv;
        f32x4 b0 = *(const f32x4*)&bias[gcol];
        f32x4 b1 = *(const f32x4*)&bias[gcol + 4];
        float v[8];
#pragma unroll
        for (int x = 0; x < 4; ++x) {
            v[x] = b2f(pc[x]) + b0[x];
            v[4 + x] = b2f(pc[4 + x]) + b1[x];
        }
        if constexpr (RES == 1) {
            u32x4 rv = *(const u32x4*)&resw[(size_t)grow * N + gcol];
            const u16* pr = (const u16*)&rv;
#pragma unroll
            for (int x = 0; x < 8; ++x) v[x] += b2f(pr[x]);
        }
        if constexpr (EPI == 1)
#pragma unroll
            for (int x = 0; x < 8; ++x)
                v[x] = 0.5f * v[x] * (1.f + erff(v[x] * 0.70710678118654752f));
        u32x4 ov;
#pragma unroll
        for (int x = 0; x < 4; ++x)
            ov[x] = (u32)f2b(v[2 * x]) | ((u32)f2b(v[2 * x + 1]) << 16);
        *(u32x4*)&Cout[(size_t)grow * N + gcol] = ov;
    }
}

// ---------------------------------------------------------------------------
// MFMA attention. One wave per (window, head). Grid 2048 x 256thr (4 waves).
// ---------------------------------------------------------------------------
__global__ __launch_bounds__(256)
void attn_mfma_kernel(const u16* __restrict__ Q, const u16* __restrict__ KV,
                      const float* __restrict__ rpb, u16* __restrict__ O) {
    __shared__ __align__(16) u16 Pq[4][64][72];
    __shared__ __align__(16) u16 Vt[4][32][72];
    __shared__ float rb[4][228];
    const int w = threadIdx.x >> 6, lane = threadIdx.x & 63;
    const int gw = blockIdx.x * 4 + w;
    const int win = gw >> 3, h = gw & 7;
    const int c = lane & 15, g = lane >> 4;
    for (int i = lane; i < 225; i += 64) rb[w][i] = rpb[i * 8 + h];
    {
        const u16* Vrow = KV + ((size_t)(win * 64 + lane)) * 512 + 256 + h * 32;
        u32x4 vv[4];
#pragma unroll
        for (int ch = 0; ch < 4; ++ch) vv[ch] = *(const u32x4*)(Vrow + ch * 8);
        const u16* pv = (const u16*)vv;
#pragma unroll
        for (int d = 0; d < 32; ++d) Vt[w][d][lane] = pv[d];
    }
    const u16* Qb = Q + ((size_t)win * 64 + c) * 256 + h * 32 + g * 8;
    const u16* Kb = KV + ((size_t)win * 64 + c) * 512 + h * 32 + g * 8;
    bf16x8 qf[4], kf[4];
#pragma unroll
    for (int t = 0; t < 4; ++t) {
        qf[t] = *(const bf16x8*)(Qb + (size_t)t * 16 * 256);
        kf[t] = *(const bf16x8*)(Kb + (size_t)t * 16 * 512);
    }
    f32x4 st[4][4];
#pragma unroll
    for (int kb = 0; kb < 4; ++kb)
#pragma unroll
        for (int qb = 0; qb < 4; ++qb) {
            f32x4 z = {0.f, 0.f, 0.f, 0.f};
            st[kb][qb] = __builtin_amdgcn_mfma_f32_16x16x32_bf16(kf[kb], qf[qb], z, 0, 0, 0);
        }
    __syncthreads();
    const float scale = 0.17677669529663687f;
    const int qy2 = c >> 3, qx = c & 7;
#pragma unroll
    for (int qb = 0; qb < 4; ++qb) {
        float sv[16];
#pragma unroll
        for (int kb = 0; kb < 4; ++kb)
#pragma unroll
            for (int r = 0; r < 4; ++r) {
                const int k = kb * 16 + 4 * g + r;
                const int dy = (qb * 2 + qy2) - (k >> 3) + 7;
                const int dx = qx - (k & 7) + 7;
                sv[kb * 4 + r] = st[kb][qb][r] * scale + rb[w][dy * 15 + dx];
            }
        float mx = sv[0];
#pragma unroll
        for (int j = 1; j < 16; ++j) mx = fmaxf(mx, sv[j]);
        mx = fmaxf(mx, __shfl_xor(mx, 16));
        mx = fmaxf(mx, __shfl_xor(mx, 32));
        float sum = 0.f;
#pragma unroll
        for (int j = 0; j < 16; ++j) {
            sv[j] = __expf(sv[j] - mx);
            sum += sv[j];
        }
        sum += __shfl_xor(sum, 16);
        sum += __shfl_xor(sum, 32);
        const float inv = 1.f / sum;
#pragma unroll
        for (int kb = 0; kb < 4; ++kb) {
            u32x2 pk;
            pk[0] = (u32)f2b(sv[kb * 4 + 0] * inv) | ((u32)f2b(sv[kb * 4 + 1] * inv) << 16);
            pk[1] = (u32)f2b(sv[kb * 4 + 2] * inv) | ((u32)f2b(sv[kb * 4 + 3] * inv) << 16);
            *(u32x2*)&Pq[w][qb * 16 + c][kb * 16 + 4 * g] = pk;
        }
    }
    __syncthreads();
    f32x4 ot[4][2] = {};
#pragma unroll
    for (int ks = 0; ks < 2; ++ks) {
        bf16x8 bfr[2];
#pragma unroll
        for (int db = 0; db < 2; ++db)
            bfr[db] = *(const bf16x8*)&Vt[w][db * 16 + c][ks * 32 + g * 8];
#pragma unroll
        for (int qb = 0; qb < 4; ++qb) {
            bf16x8 af = *(const bf16x8*)&Pq[w][qb * 16 + c][ks * 32 + g * 8];
#pragma unroll
            for (int db = 0; db < 2; ++db)
                ot[qb][db] = __builtin_amdgcn_mfma_f32_16x16x32_bf16(af, bfr[db], ot[qb][db], 0, 0, 0);
        }
    }
    u16* Ob = O + ((size_t)win * 64) * 256 + h * 32;
#pragma unroll
    for (int qb = 0; qb < 4; ++qb)
#pragma unroll
        for (int db = 0; db < 2; ++db)
#pragma unroll
            for (int r = 0; r < 4; ++r)
                Ob[(size_t)(qb * 16 + 4 * g + r) * 256 + db * 16 + c] = f2b(ot[qb][db][r]);
}

// ---------------------------------------------------------------------------
// scatter v2: window layout [1024*64,256] bf16 -> [4,256,128,128] f32.
// ---------------------------------------------------------------------------
__global__ __launch_bounds__(256)
void scatter_kernel(const u16* __restrict__ Wn, float* __restrict__ out) {
    __shared__ __align__(16) u16 win[128][264];
    const int tid = threadIdx.x;
    const int blk2 = blockIdx.x;  // 0..511
    const int b = blk2 >> 7, hb = (blk2 >> 3) & 15, wp = blk2 & 7;
    const size_t base = (size_t)((b * 16 + hb) * 16 + wp * 2) * 64 * 256;
#pragma unroll
    for (int it = 0; it < 16; ++it) {
        const int e8 = it * 256 + tid;
        const int tok = e8 >> 5, c0 = (e8 & 31) * 8;
        *(u32x4*)&win[tok][c0] = *(const u32x4*)(Wn + base + (size_t)e8 * 8);
    }
    __syncthreads();
#pragma unroll
    for (int it = 0; it < 8; ++it) {
        const int id = it * 256 + tid;
        const int c = id & 255, y = id >> 8;
        f32x4 o0, o1, o2, o3;
#pragma unroll
        for (int x = 0; x < 4; ++x) {
            o0[x] = b2f(win[y * 8 + x][c]);
            o1[x] = b2f(win[y * 8 + 4 + x][c]);
            o2[x] = b2f(win[64 + y * 8 + x][c]);
            o3[x] = b2f(win[64 + y * 8 + 4 + x][c]);
        }
        const size_t oo =
            (((size_t)(b * 256 + c) * 128) + hb * 8 + y) * 128 + wp * 16;
        *(f32x4*)(out + oo) = o0;
        *(f32x4*)(out + oo + 4) = o1;
        *(f32x4*)(out + oo + 8) = o2;
        *(f32x4*)(out + oo + 12) = o3;
    }
}

// ---------------------------------------------------------------------------
extern "C" void kernel_launch(void* const* d_in, const int* in_sizes, int n_in,
                              void* d_out, int out_size, void* d_ws,
                              size_t ws_size, hipStream_t stream) {
    const float* spatial = (const float*)d_in[0];
    const float* freq    = (const float*)d_in[1];
    const float* s_qw  = (const float*)d_in[2];
    const float* s_qb  = (const float*)d_in[3];
    const float* s_kvw = (const float*)d_in[4];
    const float* s_kvb = (const float*)d_in[5];
    const float* s_rpb = (const float*)d_in[6];
    const float* s_pw  = (const float*)d_in[7];
    const float* s_pb  = (const float*)d_in[8];
    const float* f_qw  = (const float*)d_in[9];
    const float* f_qb  = (const float*)d_in[10];
    const float* f_kvw = (const float*)d_in[11];
    const float* f_kvb = (const float*)d_in[12];
    const float* f_rpb = (const float*)d_in[13];
    const float* f_pw  = (const float*)d_in[14];
    const float* f_pb  = (const float*)d_in[15];
    const float* ns1_g = (const float*)d_in[16];
    const float* ns1_b = (const float*)d_in[17];
    const float* nfs_g = (const float*)d_in[18];
    const float* nfs_b = (const float*)d_in[19];
    const float* ns2_g = (const float*)d_in[20];
    const float* ns2_b = (const float*)d_in[21];
    const float* nf1_g = (const float*)d_in[22];
    const float* nf1_b = (const float*)d_in[23];
    const float* nsf_g = (const float*)d_in[24];
    const float* nsf_b = (const float*)d_in[25];
    const float* nf2_g = (const float*)d_in[26];
    const float* nf2_b = (const float*)d_in[27];
    const float* ffns_w1 = (const float*)d_in[28];
    const float* ffns_b1 = (const float*)d_in[29];
    const float* ffns_w2 = (const float*)d_in[30];
    const float* ffns_b2 = (const float*)d_in[31];
    const float* ffnf_w1 = (const float*)d_in[32];
    const float* ffnf_b1 = (const float*)d_in[33];
    const float* ffnf_w2 = (const float*)d_in[34];
    const float* ffnf_b2 = (const float*)d_in[35];

    float* out = (float*)d_out;
    char* ob = (char*)d_out;
    char* ws = (char*)d_ws;
    const size_t MB32 = (size_t)32 << 20;
    u16* U0  = (u16*)ob;               // 32 MiB (attn out)
    u16* U1  = (u16*)(ob + MB32);      // 32 MiB (q / s1)
    u16* U23 = (u16*)(ob + 2 * MB32);  // 64 MiB (kv / hid)
    u16* W0  = (u16*)ws;               // 32 MiB (s2, then f2)
    u16* W1  = (u16*)(ws + MB32);      // 32 MiB (f1)
    u16* WB  = (u16*)(ws + 2 * MB32);  // 2 MiB bf16 weights
    u16* R0  = (u16*)(ws + 2 * MB32 + (2 << 20));           // raw spatial win
    u16* R1  = (u16*)(ws + 2 * MB32 + (2 << 20) + MB32);    // raw freq win

    // unit layout (64Ki elems each), per wconv startmap 0xECB9864310:
    // 0:s_qw  1-2:s_kvw  3:s_pw  4-5:ffns_w1  6-7:ffns_w2
    // 8:f_qw  9-10:f_kvw 11:f_pw 12-13:ffnf_w1 14-15:ffnf_w2
    const u16* w_sq  = WB;
    const u16* w_skv = WB + 1 * 65536;
    const u16* w_sp  = WB + 3 * 65536;
    const u16* w_sw1 = WB + 4 * 65536;
    const u16* w_sw2 = WB + 6 * 65536;
    const u16* w_fq  = WB + 8 * 65536;
    const u16* w_fkv = WB + 9 * 65536;
    const u16* w_fp  = WB + 11 * 65536;
    const u16* w_fw1 = WB + 12 * 65536;
    const u16* w_fw2 = WB + 14 * 65536;

    WPack wp;
    wp.s[0] = s_qw;  wp.s[1] = s_kvw; wp.s[2] = s_pw;  wp.s[3] = ffns_w1;
    wp.s[4] = ffns_w2; wp.s[5] = f_qw; wp.s[6] = f_kvw; wp.s[7] = f_pw;
    wp.s[8] = ffnf_w1; wp.s[9] = ffnf_w2;

    const dim3 B(256);
    wconv_kernel<<<1024, B, 0, stream>>>(wp, WB);
    // --- direction 1: spatial queries attend frequency kv ---
    gather_ln_kernel<<<512, B, 0, stream>>>(spatial, ns1_g, ns1_b, U0, R0);
    gather_ln_kernel<<<512, B, 0, stream>>>(freq, nfs_g, nfs_b, U1, R1);
    gemm_kernel<256, 512, 0, 0><<<8192, B, 0, stream>>>(
        U1, w_skv, s_kvb, nullptr, U23);           // kv
    gemm_kernel<256, 256, 0, 0><<<4096, B, 0, stream>>>(
        U0, w_sq, s_qb, nullptr, U1);              // q
    attn_mfma_kernel<<<2048, B, 0, stream>>>(U1, U23, s_rpb, U0);
    gemm_kernel<256, 256, 1, 0><<<4096, B, 0, stream>>>(
        U0, w_sp, s_pb, R0, U1);                   // s1 = raw + proj
    ln_kernel<<<16384, B, 0, stream>>>(U1, ns2_g, ns2_b, U0);
    gemm_kernel<256, 512, 0, 1><<<8192, B, 0, stream>>>(
        U0, w_sw1, ffns_b1, nullptr, U23);         // hid (GELU)
    gemm_kernel<512, 256, 1, 0><<<4096, B, 0, stream>>>(
        U23, w_sw2, ffns_b2, U1, W0);              // s2 = s1 + mlp
    // --- direction 2: frequency queries attend updated spatial kv ---
    ln_kernel<<<16384, B, 0, stream>>>(W0, nsf_g, nsf_b, U0);  // ln_nsf(s2)
    gemm_kernel<256, 512, 0, 0><<<8192, B, 0, stream>>>(
        U0, w_fkv, f_kvb, nullptr, U23);           // kv2
    ln_kernel<<<16384, B, 0, stream>>>(R1, nf1_g, nf1_b, U0);  // ln_nf1(f)
    gemm_kernel<256, 256, 0, 0><<<4096, B, 0, stream>>>(
        U0, w_fq, f_qb, nullptr, U1);              // q2
    attn_mfma_kernel<<<2048, B, 0, stream>>>(U1, U23, f_rpb, U0);
    gemm_kernel<256, 256, 1, 0><<<4096, B, 0, stream>>>(
        U0, w_fp, f_pb, R1, W1);                   // f1 = raw + proj
    ln_kernel<<<16384, B, 0, stream>>>(W1, nf2_g, nf2_b, U0);
    gemm_kernel<256, 512, 0, 1><<<8192, B, 0, stream>>>(
        U0, w_fw1, ffnf_b1, nullptr, U23);         // hid2 (GELU)
    scatter_kernel<<<512, B, 0, stream>>>(W0, out);  // spatial_out
    gemm_kernel<512, 256, 1, 0><<<4096, B, 0, stream>>>(
        U23, w_fw2, ffnf_b2, W1, W0);              // f2 = f1 + mlp
    scatter_kernel<<<512, B, 0, stream>>>(W0, out + 16777216);  // freq_out
}

// Round 18
// 562.832 us; speedup vs baseline: 2.0104x; 1.0376x over previous
//
#include <hip/hip_runtime.h>

typedef unsigned short u16;
typedef unsigned int u32;
typedef unsigned long long u64;
using bf16x8 = __attribute__((ext_vector_type(8))) short;
using f32x4  = __attribute__((ext_vector_type(4))) float;
using u32x4  = __attribute__((ext_vector_type(4))) u32;
using u32x2  = __attribute__((ext_vector_type(2))) u32;

__device__ __forceinline__ float b2f(u16 h) {
    u32 u = ((u32)h) << 16;
    float f;
    __builtin_memcpy(&f, &u, 4);
    return f;
}
__device__ __forceinline__ u16 f2b(float f) {
    u32 u;
    __builtin_memcpy(&u, &f, 4);
    u32 r = (u + 0x7fffu + ((u >> 16) & 1u)) >> 16;
    return (u16)r;
}
__device__ __forceinline__ void gload16(const u16* g, u16* l) {
    __builtin_amdgcn_global_load_lds(
        (const __attribute__((address_space(1))) u32*)g,
        (__attribute__((address_space(3))) u32*)l, 16, 0, 0);
}
// Barrier fenced on BOTH sides (s_barrier is not a compiler fence).
__device__ __forceinline__ void hard_barrier() {
    asm volatile("" ::: "memory");
    __builtin_amdgcn_sched_barrier(0);
    __builtin_amdgcn_s_barrier();
    __builtin_amdgcn_sched_barrier(0);
    asm volatile("" ::: "memory");
}

// ---------------------------------------------------------------------------
// wconv v2: convert 10 f32 weight matrices to bf16 (2 MiB buffer), folding
// the LN gain into the K-columns of the 6 LN-consumer weights (all K=256).
// ---------------------------------------------------------------------------
struct WPack { const float* s[10]; const float* gn[10]; };

__global__ __launch_bounds__(256)
void wconv_kernel(WPack p, u16* __restrict__ dst) {
    const int id = blockIdx.x * 256 + threadIdx.x;  // 0..262143
    const int e = id * 4;
    const int unit = e >> 16;  // 0..15
    const u64 arrmap = 0x9988766544332110ull;
    const u64 startmap = 0xECB9864310ull;  // start unit of arr (nibbles)
    const int arr = (int)((arrmap >> (unit * 4)) & 15);
    const int start = (int)((startmap >> (arr * 4)) & 15);
    const int off = e - (start << 16);
    f32x4 v = *(const f32x4*)(p.s[arr] + off);
    const float* gp = p.gn[arr];
    if (gp) {
        f32x4 gv = *(const f32x4*)(gp + (off & 255));
        v[0] *= gv[0]; v[1] *= gv[1]; v[2] *= gv[2]; v[3] *= gv[3];
    }
    u32x2 w;
    w[0] = (u32)f2b(v[0]) | ((u32)f2b(v[1]) << 16);
    w[1] = (u32)f2b(v[2]) | ((u32)f2b(v[3]) << 16);
    *(u32x2*)(dst + e) = w;
}

// ---------------------------------------------------------------------------
// gb: per-output-column LN-correction vectors for the 6 LN-consumer GEMMs.
// G[n] = sum_c g_c*W_nc ; B[n] = sum_c beta_c*W_nc. One wave per n (2560).
// ---------------------------------------------------------------------------
struct GBPack { const float* w[6]; const float* g[6]; const float* bt[6];
                int nstart[7]; };

__global__ __launch_bounds__(256)
void gb_kernel(GBPack p, float* __restrict__ G, float* __restrict__ Bv) {
    const int wid = blockIdx.x * 4 + (threadIdx.x >> 6);
    const int lane = threadIdx.x & 63;
    int i = 0;
    while (i < 5 && wid >= p.nstart[i + 1]) ++i;
    const int nl = wid - p.nstart[i];
    const float* wr = p.w[i] + (size_t)nl * 256;
    const float* gr = p.g[i];
    const float* br = p.bt[i];
    float s = 0.f, t = 0.f;
#pragma unroll
    for (int x = 0; x < 4; ++x) {
        const float wv = wr[lane * 4 + x];
        s += gr[lane * 4 + x] * wv;
        t += br[lane * 4 + x] * wv;
    }
#pragma unroll
    for (int o = 32; o; o >>= 1) {
        s += __shfl_xor(s, o);
        t += __shfl_xor(t, o);
    }
    if (!lane) { G[wid] = s; Bv[wid] = t; }
}

// ---------------------------------------------------------------------------
// gather_stats: window-partition [4,256,128,128] f32 -> raw bf16 window
// layout [1024*64,256] + per-token LN stats (mean, rstd). One block per
// window PAIR: full-64B-line reads, linear 16B writes.
// ---------------------------------------------------------------------------
__global__ __launch_bounds__(256)
void gather_stats_kernel(const float* __restrict__ X, u16* __restrict__ raw,
                         float* __restrict__ SS) {
    __shared__ __align__(16) u16 win[128][264];  // [w2*64 + y*8 + x][c]
    const int tid = threadIdx.x;
    const int blk2 = blockIdx.x;  // 0..511
    const int b = blk2 >> 7, hb = (blk2 >> 3) & 15, wp = blk2 & 7;
#pragma unroll
    for (int it = 0; it < 8; ++it) {
        const int id = it * 256 + tid;
        const int c = id & 255, y = id >> 8;
        const size_t off =
            (((size_t)(b * 256 + c) * 128) + hb * 8 + y) * 128 + wp * 16;
        f32x4 v0 = *(const f32x4*)(X + off);
        f32x4 v1 = *(const f32x4*)(X + off + 4);
        f32x4 v2 = *(const f32x4*)(X + off + 8);
        f32x4 v3 = *(const f32x4*)(X + off + 12);
#pragma unroll
        for (int x = 0; x < 4; ++x) {
            win[y * 8 + x][c] = f2b(v0[x]);
            win[y * 8 + 4 + x][c] = f2b(v1[x]);
            win[64 + y * 8 + x][c] = f2b(v2[x]);
            win[64 + y * 8 + 4 + x][c] = f2b(v3[x]);
        }
    }
    __syncthreads();
    const size_t btok = (size_t)((b * 16 + hb) * 16 + wp * 2) * 64;
    {
        const int tok = tid >> 1, half = tid & 1;
        float s = 0.f, s2 = 0.f;
#pragma unroll
        for (int i = 0; i < 16; ++i) {
            u32x4 rv = *(const u32x4*)&win[tok][half * 128 + i * 8];
            const u16* pv = (const u16*)&rv;
#pragma unroll
            for (int x = 0; x < 8; ++x) {
                float v = b2f(pv[x]);
                s += v;
                s2 += v * v;
            }
        }
        s += __shfl_xor(s, 1);
        s2 += __shfl_xor(s2, 1);
        const float mean = s * (1.f / 256.f);
        const float var = s2 * (1.f / 256.f) - mean * mean;
        if (!half) {
            SS[(btok + tok) * 2] = mean;
            SS[(btok + tok) * 2 + 1] = rsqrtf(var + 1e-5f);
        }
    }
    const size_t base = btok * 256;
#pragma unroll
    for (int it = 0; it < 16; ++it) {
        const int e8 = it * 256 + tid;
        const int tok = e8 >> 5, c0 = (e8 & 31) * 8;
        *(u32x4*)(raw + base + (size_t)e8 * 8) = *(const u32x4*)&win[tok][c0];
    }
}

// ---------------------------------------------------------------------------
// stats: per-token LN stats of [65536,256] bf16. One wave per token.
// ---------------------------------------------------------------------------
__global__ __launch_bounds__(256)
void stats_kernel(const u16* __restrict__ X, float* __restrict__ SS) {
    const int wave = threadIdx.x >> 6, lane = threadIdx.x & 63;
    const size_t tok = (size_t)blockIdx.x * 4 + wave;
    u32x2 v = *(const u32x2*)(X + tok * 256 + lane * 4);
    float f0 = b2f((u16)(v[0] & 0xffff)), f1 = b2f((u16)(v[0] >> 16));
    float f2v = b2f((u16)(v[1] & 0xffff)), f3 = b2f((u16)(v[1] >> 16));
    float s = f0 + f1 + f2v + f3;
    float s2 = f0 * f0 + f1 * f1 + f2v * f2v + f3 * f3;
#pragma unroll
    for (int off = 32; off; off >>= 1) {
        s += __shfl_xor(s, off);
        s2 += __shfl_xor(s2, off);
    }
    if (!lane) {
        const float mean = s * (1.f / 256.f);
        const float var = s2 * (1.f / 256.f) - mean * mean;
        SS[tok * 2] = mean;
        SS[tok * 2 + 1] = rsqrtf(var + 1e-5f);
    }
}

// ---------------------------------------------------------------------------
// GEMM v8: C[M,N] = A'[M,K] @ W[N,K]^T + bias. Tile 64x64, 256 thr, BK=64
// dbuf (32 KB LDS, 5 blk/CU), counted vmcnt(4), hard barriers.
// LNE=1: W is pre-folded (W*g) and the LN correction is applied in the
//   epilogue: y = rstd*acc - mean*rstd*G[n] + B[n] + bias[n]  (per-row
//   mean/rstd from stats[]). Hot loop identical to LNE=0.
// RES: 0=none, 1=+bf16 windowed residual. EPI: 0=none, 1=GELU(exact).
// ---------------------------------------------------------------------------
template <int K, int N, int LNE, int RES, int EPI>
__global__ __launch_bounds__(256)
void gemm_kernel(const u16* __restrict__ A, const u16* __restrict__ Wt,
                 const float* __restrict__ bias, const float* __restrict__ stats,
                 const float* __restrict__ Gv, const float* __restrict__ Bv,
                 const u16* __restrict__ resw, u16* __restrict__ Cout) {
    constexpr int S = N / 64;    // N-strips
    constexpr int NPH = K / 64;  // phases (4 or 8)
    __shared__ __align__(16) u16 As[2][64 * 64];
    __shared__ __align__(16) u16 Bs[2][64 * 64];
    const int tid = threadIdx.x;
    const int lane = tid & 63, w = tid >> 6;
    const int cl = lane & 15, g = lane >> 4;
    const int wr = w >> 1, wc = w & 1;
    const int bid = blockIdx.x;
    const int xcd = bid & 7, rest = bid >> 3;
    const int strip = rest % S, mseq = rest / S;
    const int m0 = (xcd * 128 + mseq) * 64;  // M-tile (1024 total)
    const int n0 = strip * 64;
    const int rowg = lane >> 3;   // row within staged 8-row group
    const int sch = lane & 7;     // 16B chunk within 128B row
    f32x4 acc[2][2] = {};

    auto stage = [&](int c) {
        const int buf = c & 1;
#pragma unroll
        for (int it = 0; it < 2; ++it) {
            const int rp = w * 16 + it * 8;
            const int row = rp + rowg;
            const int ch = sch ^ (row & 7);  // pre-swizzled source chunk
            gload16(&A[(size_t)(m0 + row) * K + c * 64 + ch * 8],
                    &As[buf][rp * 64]);
            gload16(&Wt[(size_t)(n0 + row) * K + c * 64 + ch * 8],
                    &Bs[buf][rp * 64]);
        }
    };
    stage(0);
    stage(1);
#pragma unroll
    for (int c = 0; c < NPH; ++c) {
        if (c + 1 < NPH)
            asm volatile("s_waitcnt vmcnt(4)" ::: "memory");  // stage(c) done
        else
            asm volatile("s_waitcnt vmcnt(0)" ::: "memory");
        hard_barrier();
        const u16* Ab = &As[c & 1][0];
        const u16* Bb = &Bs[c & 1][0];
#pragma unroll
        for (int ks = 0; ks < 2; ++ks) {
            const int J = ks * 4 + g;  // 16B chunk of row (0..7)
            bf16x8 af[2], bw[2];
#pragma unroll
            for (int i = 0; i < 2; ++i) {
                const int r = wr * 32 + i * 16 + cl;
                af[i] = *(const bf16x8*)(Ab + r * 64 + (J ^ (r & 7)) * 8);
            }
#pragma unroll
            for (int j = 0; j < 2; ++j) {
                const int r = wc * 32 + j * 16 + cl;
                bw[j] = *(const bf16x8*)(Bb + r * 64 + (J ^ (r & 7)) * 8);
            }
#pragma unroll
            for (int i = 0; i < 2; ++i)
#pragma unroll
                for (int j = 0; j < 2; ++j)
                    acc[i][j] = __builtin_amdgcn_mfma_f32_16x16x32_bf16(
                        af[i], bw[j], acc[i][j], 0, 0, 0);
        }
        asm volatile("s_waitcnt lgkmcnt(0)" ::: "memory");
        hard_barrier();
        if (c + 2 < NPH) stage(c + 2);
    }
    // ---- epilogue: acc -> LDS (reuse As) -> coalesced 16B stores ----
    u16 (*Cs)[72] = (u16(*)[72])&As[0][0];
#pragma unroll
    for (int i = 0; i < 2; ++i)
#pragma unroll
        for (int j = 0; j < 2; ++j)
#pragma unroll
            for (int rr = 0; rr < 4; ++rr)
                Cs[wr * 32 + i * 16 + g * 4 + rr][wc * 32 + j * 16 + cl] =
                    f2b(acc[i][j][rr]);
    __syncthreads();
#pragma unroll
    for (int it = 0; it < 2; ++it) {
        const int idx = it * 256 + tid;
        const int row = idx >> 3, ch = idx & 7;
        const int grow = m0 + row, gcol = n0 + ch * 8;
        u32x4 cv = *(const u32x4*)&Cs[row][ch * 8];
        const u16* pc = (const u16*)&cv;
        f32x4 b0 = *(const f32x4*)&bias[gcol];
        f32x4 b1 = *(const f32x4*)&bias[gcol + 4];
        float v[8];
        if constexpr (LNE) {
            const float mean = stats[2 * (size_t)grow];
            const float rstd = stats[2 * (size_t)grow + 1];
            const float mr = mean * rstd;
            f32x4 G0 = *(const f32x4*)&Gv[gcol];
            f32x4 G1 = *(const f32x4*)&Gv[gcol + 4];
            f32x4 B0 = *(const f32x4*)&Bv[gcol];
            f32x4 B1 = *(const f32x4*)&Bv[gcol + 4];
#pragma unroll
            for (int x = 0; x < 4; ++x) {
                v[x] = rstd * b2f(pc[x]) - mr * G0[x] + B0[x] + b0[x];
                v[4 + x] = rstd * b2f(pc[4 + x]) - mr * G1[x] + B1[x] + b1[x];
            }
        } else {
#pragma unroll
            for (int x = 0; x < 4; ++x) {
                v[x] = b2f(pc[x]) + b0[x];
                v[4 + x] = b2f(pc[4 + x]) + b1[x];
            }
        }
        if constexpr (RES == 1) {
            u32x4 rv = *(const u32x4*)&resw[(size_t)grow * N + gcol];
            const u16* pr = (const u16*)&rv;
#pragma unroll
            for (int x = 0; x < 8; ++x) v[x] += b2f(pr[x]);
        }
        if constexpr (EPI == 1)
#pragma unroll
            for (int x = 0; x < 8; ++x)
                v[x] = 0.5f * v[x] * (1.f + erff(v[x] * 0.70710678118654752f));
        u32x4 ov;
#pragma unroll
        for (int x = 0; x < 4; ++x)
            ov[x] = (u32)f2b(v[2 * x]) | ((u32)f2b(v[2 * x + 1]) << 16);
        *(u32x4*)&Cout[(size_t)grow * N + gcol] = ov;
    }
}

// ---------------------------------------------------------------------------
// MFMA attention. One wave per (window, head). Grid 2048 x 256thr (4 waves).
// ---------------------------------------------------------------------------
__global__ __launch_bounds__(256)
void attn_mfma_kernel(const u16* __restrict__ Q, const u16* __restrict__ KV,
                      const float* __restrict__ rpb, u16* __restrict__ O) {
    __shared__ __align__(16) u16 Pq[4][64][72];
    __shared__ __align__(16) u16 Vt[4][32][72];
    __shared__ float rb[4][228];
    const int w = threadIdx.x >> 6, lane = threadIdx.x & 63;
    const int gw = blockIdx.x * 4 + w;
    const int win = gw >> 3, h = gw & 7;
    const int c = lane & 15, g = lane >> 4;
    for (int i = lane; i < 225; i += 64) rb[w][i] = rpb[i * 8 + h];
    {
        const u16* Vrow = KV + ((size_t)(win * 64 + lane)) * 512 + 256 + h * 32;
        u32x4 vv[4];
#pragma unroll
        for (int ch = 0; ch < 4; ++ch) vv[ch] = *(const u32x4*)(Vrow + ch * 8);
        const u16* pv = (const u16*)vv;
#pragma unroll
        for (int d = 0; d < 32; ++d) Vt[w][d][lane] = pv[d];
    }
    const u16* Qb = Q + ((size_t)win * 64 + c) * 256 + h * 32 + g * 8;
    const u16* Kb = KV + ((size_t)win * 64 + c) * 512 + h * 32 + g * 8;
    bf16x8 qf[4], kf[4];
#pragma unroll
    for (int t = 0; t < 4; ++t) {
        qf[t] = *(const bf16x8*)(Qb + (size_t)t * 16 * 256);
        kf[t] = *(const bf16x8*)(Kb + (size_t)t * 16 * 512);
    }
    f32x4 st[4][4];
#pragma unroll
    for (int kb = 0; kb < 4; ++kb)
#pragma unroll
        for (int qb = 0; qb < 4; ++qb) {
            f32x4 z = {0.f, 0.f, 0.f, 0.f};
            st[kb][qb] = __builtin_amdgcn_mfma_f32_16x16x32_bf16(kf[kb], qf[qb], z, 0, 0, 0);
        }
    __syncthreads();
    const float scale = 0.17677669529663687f;
    const int qy2 = c >> 3, qx = c & 7;
#pragma unroll
    for (int qb = 0; qb < 4; ++qb) {
        float sv[16];
#pragma unroll
        for (int kb = 0; kb < 4; ++kb)
#pragma unroll
            for (int r = 0; r < 4; ++r) {
                const int k = kb * 16 + 4 * g + r;
                const int dy = (qb * 2 + qy2) - (k >> 3) + 7;
                const int dx = qx - (k & 7) + 7;
                sv[kb * 4 + r] = st[kb][qb][r] * scale + rb[w][dy * 15 + dx];
            }
        float mx = sv[0];
#pragma unroll
        for (int j = 1; j < 16; ++j) mx = fmaxf(mx, sv[j]);
        mx = fmaxf(mx, __shfl_xor(mx, 16));
        mx = fmaxf(mx, __shfl_xor(mx, 32));
        float sum = 0.f;
#pragma unroll
        for (int j = 0; j < 16; ++j) {
            sv[j] = __expf(sv[j] - mx);
            sum += sv[j];
        }
        sum += __shfl_xor(sum, 16);
        sum += __shfl_xor(sum, 32);
        const float inv = 1.f / sum;
#pragma unroll
        for (int kb = 0; kb < 4; ++kb) {
            u32x2 pk;
            pk[0] = (u32)f2b(sv[kb * 4 + 0] * inv) | ((u32)f2b(sv[kb * 4 + 1] * inv) << 16);
            pk[1] = (u32)f2b(sv[kb * 4 + 2] * inv) | ((u32)f2b(sv[kb * 4 + 3] * inv) << 16);
            *(u32x2*)&Pq[w][qb * 16 + c][kb * 16 + 4 * g] = pk;
        }
    }
    __syncthreads();
    f32x4 ot[4][2] = {};
#pragma unroll
    for (int ks = 0; ks < 2; ++ks) {
        bf16x8 bfr[2];
#pragma unroll
        for (int db = 0; db < 2; ++db)
            bfr[db] = *(const bf16x8*)&Vt[w][db * 16 + c][ks * 32 + g * 8];
#pragma unroll
        for (int qb = 0; qb < 4; ++qb) {
            bf16x8 af = *(const bf16x8*)&Pq[w][qb * 16 + c][ks * 32 + g * 8];
#pragma unroll
            for (int db = 0; db < 2; ++db)
                ot[qb][db] = __builtin_amdgcn_mfma_f32_16x16x32_bf16(af, bfr[db], ot[qb][db], 0, 0, 0);
        }
    }
    u16* Ob = O + ((size_t)win * 64) * 256 + h * 32;
#pragma unroll
    for (int qb = 0; qb < 4; ++qb)
#pragma unroll
        for (int db = 0; db < 2; ++db)
#pragma unroll
            for (int r = 0; r < 4; ++r)
                Ob[(size_t)(qb * 16 + 4 * g + r) * 256 + db * 16 + c] = f2b(ot[qb][db][r]);
}

// ---------------------------------------------------------------------------
// scatter v2: window layout [1024*64,256] bf16 -> [4,256,128,128] f32.
// ---------------------------------------------------------------------------
__global__ __launch_bounds__(256)
void scatter_kernel(const u16* __restrict__ Wn, float* __restrict__ out) {
    __shared__ __align__(16) u16 win[128][264];
    const int tid = threadIdx.x;
    const int blk2 = blockIdx.x;  // 0..511
    const int b = blk2 >> 7, hb = (blk2 >> 3) & 15, wp = blk2 & 7;
    const size_t base = (size_t)((b * 16 + hb) * 16 + wp * 2) * 64 * 256;
#pragma unroll
    for (int it = 0; it < 16; ++it) {
        const int e8 = it * 256 + tid;
        const int tok = e8 >> 5, c0 = (e8 & 31) * 8;
        *(u32x4*)&win[tok][c0] = *(const u32x4*)(Wn + base + (size_t)e8 * 8);
    }
    __syncthreads();
#pragma unroll
    for (int it = 0; it < 8; ++it) {
        const int id = it * 256 + tid;
        const int c = id & 255, y = id >> 8;
        f32x4 o0, o1, o2, o3;
#pragma unroll
        for (int x = 0; x < 4; ++x) {
            o0[x] = b2f(win[y * 8 + x][c]);
            o1[x] = b2f(win[y * 8 + 4 + x][c]);
            o2[x] = b2f(win[64 + y * 8 + x][c]);
            o3[x] = b2f(win[64 + y * 8 + 4 + x][c]);
        }
        const size_t oo =
            (((size_t)(b * 256 + c) * 128) + hb * 8 + y) * 128 + wp * 16;
        *(f32x4*)(out + oo) = o0;
        *(f32x4*)(out + oo + 4) = o1;
        *(f32x4*)(out + oo + 8) = o2;
        *(f32x4*)(out + oo + 12) = o3;
    }
}

// ---------------------------------------------------------------------------
extern "C" void kernel_launch(void* const* d_in, const int* in_sizes, int n_in,
                              void* d_out, int out_size, void* d_ws,
                              size_t ws_size, hipStream_t stream) {
    const float* spatial = (const float*)d_in[0];
    const float* freq    = (const float*)d_in[1];
    const float* s_qw  = (const float*)d_in[2];
    const float* s_qb  = (const float*)d_in[3];
    const float* s_kvw = (const float*)d_in[4];
    const float* s_kvb = (const float*)d_in[5];
    const float* s_rpb = (const float*)d_in[6];
    const float* s_pw  = (const float*)d_in[7];
    const float* s_pb  = (const float*)d_in[8];
    const float* f_qw  = (const float*)d_in[9];
    const float* f_qb  = (const float*)d_in[10];
    const float* f_kvw = (const float*)d_in[11];
    const float* f_kvb = (const float*)d_in[12];
    const float* f_rpb = (const float*)d_in[13];
    const float* f_pw  = (const float*)d_in[14];
    const float* f_pb  = (const float*)d_in[15];
    const float* ns1_g = (const float*)d_in[16];
    const float* ns1_b = (const float*)d_in[17];
    const float* nfs_g = (const float*)d_in[18];
    const float* nfs_b = (const float*)d_in[19];
    const float* ns2_g = (const float*)d_in[20];
    const float* ns2_b = (const float*)d_in[21];
    const float* nf1_g = (const float*)d_in[22];
    const float* nf1_b = (const float*)d_in[23];
    const float* nsf_g = (const float*)d_in[24];
    const float* nsf_b = (const float*)d_in[25];
    const float* nf2_g = (const float*)d_in[26];
    const float* nf2_b = (const float*)d_in[27];
    const float* ffns_w1 = (const float*)d_in[28];
    const float* ffns_b1 = (const float*)d_in[29];
    const float* ffns_w2 = (const float*)d_in[30];
    const float* ffns_b2 = (const float*)d_in[31];
    const float* ffnf_w1 = (const float*)d_in[32];
    const float* ffnf_b1 = (const float*)d_in[33];
    const float* ffnf_w2 = (const float*)d_in[34];
    const float* ffnf_b2 = (const float*)d_in[35];

    float* out = (float*)d_out;
    char* ob = (char*)d_out;
    char* ws = (char*)d_ws;
    const size_t MB32 = (size_t)32 << 20;
    u16* U0  = (u16*)ob;               // 32 MiB (attn out)
    u16* U1  = (u16*)(ob + MB32);      // 32 MiB (q / s1)
    u16* U23 = (u16*)(ob + 2 * MB32);  // 64 MiB (kv / hid)
    u16* W0  = (u16*)ws;               // 32 MiB (s2, then f2)
    u16* W1  = (u16*)(ws + MB32);      // 32 MiB (f1)
    u16* WB  = (u16*)(ws + 2 * MB32);  // 2 MiB bf16 weights
    u16* R0  = (u16*)(ws + 2 * MB32 + (2 << 20));         // raw spatial win
    u16* R1  = (u16*)(ws + 2 * MB32 + (2 << 20) + MB32);  // raw freq win
    char* SSB = ws + 2 * MB32 + (2 << 20) + 2 * MB32;     // stats area
    float* SS0 = (float*)SSB;                  // spatial stats (512 KB)
    float* SS1 = (float*)(SSB + (512 << 10));  // freq stats
    float* SS2 = (float*)(SSB + (1024 << 10)); // s1 stats
    float* SS3 = (float*)(SSB + (1536 << 10)); // s2 stats
    float* SS4 = (float*)(SSB + (2048 << 10)); // f1 stats
    float* Gv  = (float*)(SSB + (2560 << 10)); // 2560 f32
    float* Bv  = Gv + 2560;

    // unit layout (64Ki elems each), per wconv startmap 0xECB9864310:
    // 0:s_qw  1-2:s_kvw  3:s_pw  4-5:ffns_w1  6-7:ffns_w2
    // 8:f_qw  9-10:f_kvw 11:f_pw 12-13:ffnf_w1 14-15:ffnf_w2
    const u16* w_sq  = WB;
    const u16* w_skv = WB + 1 * 65536;
    const u16* w_sp  = WB + 3 * 65536;
    const u16* w_sw1 = WB + 4 * 65536;
    const u16* w_sw2 = WB + 6 * 65536;
    const u16* w_fq  = WB + 8 * 65536;
    const u16* w_fkv = WB + 9 * 65536;
    const u16* w_fp  = WB + 11 * 65536;
    const u16* w_fw1 = WB + 12 * 65536;
    const u16* w_fw2 = WB + 14 * 65536;

    WPack wp;
    wp.s[0] = s_qw;    wp.gn[0] = ns1_g;
    wp.s[1] = s_kvw;   wp.gn[1] = nfs_g;
    wp.s[2] = s_pw;    wp.gn[2] = nullptr;
    wp.s[3] = ffns_w1; wp.gn[3] = ns2_g;
    wp.s[4] = ffns_w2; wp.gn[4] = nullptr;
    wp.s[5] = f_qw;    wp.gn[5] = nf1_g;
    wp.s[6] = f_kvw;   wp.gn[6] = nsf_g;
    wp.s[7] = f_pw;    wp.gn[7] = nullptr;
    wp.s[8] = ffnf_w1; wp.gn[8] = nf2_g;
    wp.s[9] = ffnf_w2; wp.gn[9] = nullptr;

    // G/B table order: sq(256), skv(512), sw1(512), fq(256), fkv(512), fw1(512)
    GBPack gp;
    gp.w[0] = s_qw;    gp.g[0] = ns1_g; gp.bt[0] = ns1_b;
    gp.w[1] = s_kvw;   gp.g[1] = nfs_g; gp.bt[1] = nfs_b;
    gp.w[2] = ffns_w1; gp.g[2] = ns2_g; gp.bt[2] = ns2_b;
    gp.w[3] = f_qw;    gp.g[3] = nf1_g; gp.bt[3] = nf1_b;
    gp.w[4] = f_kvw;   gp.g[4] = nsf_g; gp.bt[4] = nsf_b;
    gp.w[5] = ffnf_w1; gp.g[5] = nf2_g; gp.bt[5] = nf2_b;
    gp.nstart[0] = 0;    gp.nstart[1] = 256;  gp.nstart[2] = 768;
    gp.nstart[3] = 1280; gp.nstart[4] = 1536; gp.nstart[5] = 2048;
    gp.nstart[6] = 2560;
    const float* G_sq  = Gv + 0;    const float* B_sq  = Bv + 0;
    const float* G_skv = Gv + 256;  const float* B_skv = Bv + 256;
    const float* G_sw1 = Gv + 768;  const float* B_sw1 = Bv + 768;
    const float* G_fq  = Gv + 1280; const float* B_fq  = Bv + 1280;
    const float* G_fkv = Gv + 1536; const float* B_fkv = Bv + 1536;
    const float* G_fw1 = Gv + 2048; const float* B_fw1 = Bv + 2048;

    const dim3 B(256);
    wconv_kernel<<<1024, B, 0, stream>>>(wp, WB);
    gb_kernel<<<640, B, 0, stream>>>(gp, Gv, Bv);
    gather_stats_kernel<<<512, B, 0, stream>>>(spatial, R0, SS0);
    gather_stats_kernel<<<512, B, 0, stream>>>(freq, R1, SS1);
    // --- direction 1: spatial queries attend frequency kv ---
    gemm_kernel<256, 512, 1, 0, 0><<<8192, B, 0, stream>>>(
        R1, w_skv, s_kvb, SS1, G_skv, B_skv, nullptr, U23);   // kv
    gemm_kernel<256, 256, 1, 0, 0><<<4096, B, 0, stream>>>(
        R0, w_sq, s_qb, SS0, G_sq, B_sq, nullptr, U1);        // q
    attn_mfma_kernel<<<2048, B, 0, stream>>>(U1, U23, s_rpb, U0);
    gemm_kernel<256, 256, 0, 1, 0><<<4096, B, 0, stream>>>(
        U0, w_sp, s_pb, nullptr, nullptr, nullptr, R0, U1);   // s1
    stats_kernel<<<16384, B, 0, stream>>>(U1, SS2);
    gemm_kernel<256, 512, 1, 0, 1><<<8192, B, 0, stream>>>(
        U1, w_sw1, ffns_b1, SS2, G_sw1, B_sw1, nullptr, U23); // hid (GELU)
    gemm_kernel<512, 256, 0, 1, 0><<<4096, B, 0, stream>>>(
        U23, w_sw2, ffns_b2, nullptr, nullptr, nullptr, U1, W0);  // s2
    stats_kernel<<<16384, B, 0, stream>>>(W0, SS3);
    // --- direction 2: frequency queries attend updated spatial kv ---
    gemm_kernel<256, 512, 1, 0, 0><<<8192, B, 0, stream>>>(
        W0, w_fkv, f_kvb, SS3, G_fkv, B_fkv, nullptr, U23);   // kv2
    gemm_kernel<256, 256, 1, 0, 0><<<4096, B, 0, stream>>>(
        R1, w_fq, f_qb, SS1, G_fq, B_fq, nullptr, U1);        // q2
    attn_mfma_kernel<<<2048, B, 0, stream>>>(U1, U23, f_rpb, U0);
    gemm_kernel<256, 256, 0, 1, 0><<<4096, B, 0, stream>>>(
        U0, w_fp, f_pb, nullptr, nullptr, nullptr, R1, W1);   // f1
    stats_kernel<<<16384, B, 0, stream>>>(W1, SS4);
    gemm_kernel<256, 512, 1, 0, 1><<<8192, B, 0, stream>>>(
        W1, w_fw1, ffnf_b1, SS4, G_fw1, B_fw1, nullptr, U23); // hid2 (GELU)
    scatter_kernel<<<512, B, 0, stream>>>(W0, out);           // spatial_out
    gemm_kernel<512, 256, 0, 1, 0><<<4096, B, 0, stream>>>(
        U23, w_fw2, ffnf_b2, nullptr, nullptr, nullptr, W1, W0);  // f2
    scatter_kernel<<<512, B, 0, stream>>>(W0, out + 16777216);    // freq_out
}

// Round 19
// 532.917 us; speedup vs baseline: 2.1233x; 1.0561x over previous
//
#include <hip/hip_runtime.h>

typedef unsigned short u16;
typedef unsigned int u32;
typedef unsigned long long u64;
using bf16x8 = __attribute__((ext_vector_type(8))) short;
using f32x4  = __attribute__((ext_vector_type(4))) float;
using u32x4  = __attribute__((ext_vector_type(4))) u32;
using u32x2  = __attribute__((ext_vector_type(2))) u32;

__device__ __forceinline__ float b2f(u16 h) {
    u32 u = ((u32)h) << 16;
    float f;
    __builtin_memcpy(&f, &u, 4);
    return f;
}
__device__ __forceinline__ u16 f2b(float f) {
    u32 u;
    __builtin_memcpy(&u, &f, 4);
    u32 r = (u + 0x7fffu + ((u >> 16) & 1u)) >> 16;
    return (u16)r;
}
__device__ __forceinline__ void gload16(const u16* g, u16* l) {
    __builtin_amdgcn_global_load_lds(
        (const __attribute__((address_space(1))) u32*)g,
        (__attribute__((address_space(3))) u32*)l, 16, 0, 0);
}
// Barrier fenced on BOTH sides (s_barrier is not a compiler fence).
__device__ __forceinline__ void hard_barrier() {
    asm volatile("" ::: "memory");
    __builtin_amdgcn_sched_barrier(0);
    __builtin_amdgcn_s_barrier();
    __builtin_amdgcn_sched_barrier(0);
    asm volatile("" ::: "memory");
}

// ---------------------------------------------------------------------------
// wconv v2: convert 10 f32 weight matrices to bf16 (2 MiB buffer), folding
// the LN gain into the K-columns of the 6 LN-consumer weights (all K=256).
// ---------------------------------------------------------------------------
struct WPack { const float* s[10]; const float* gn[10]; };

__global__ __launch_bounds__(256)
void wconv_kernel(WPack p, u16* __restrict__ dst) {
    const int id = blockIdx.x * 256 + threadIdx.x;  // 0..262143
    const int e = id * 4;
    const int unit = e >> 16;  // 0..15
    const u64 arrmap = 0x9988766544332110ull;
    const u64 startmap = 0xECB9864310ull;  // start unit of arr (nibbles)
    const int arr = (int)((arrmap >> (unit * 4)) & 15);
    const int start = (int)((startmap >> (arr * 4)) & 15);
    const int off = e - (start << 16);
    f32x4 v = *(const f32x4*)(p.s[arr] + off);
    const float* gp = p.gn[arr];
    if (gp) {
        f32x4 gv = *(const f32x4*)(gp + (off & 255));
        v[0] *= gv[0]; v[1] *= gv[1]; v[2] *= gv[2]; v[3] *= gv[3];
    }
    u32x2 w;
    w[0] = (u32)f2b(v[0]) | ((u32)f2b(v[1]) << 16);
    w[1] = (u32)f2b(v[2]) | ((u32)f2b(v[3]) << 16);
    *(u32x2*)(dst + e) = w;
}

// ---------------------------------------------------------------------------
// gb: per-output-column LN-correction vectors for the 6 LN-consumer GEMMs.
// G[n] = sum_c g_c*W_nc ; B[n] = sum_c beta_c*W_nc. One wave per n (2560).
// ---------------------------------------------------------------------------
struct GBPack { const float* w[6]; const float* g[6]; const float* bt[6];
                int nstart[7]; };

__global__ __launch_bounds__(256)
void gb_kernel(GBPack p, float* __restrict__ G, float* __restrict__ Bv) {
    const int wid = blockIdx.x * 4 + (threadIdx.x >> 6);
    const int lane = threadIdx.x & 63;
    int i = 0;
    while (i < 5 && wid >= p.nstart[i + 1]) ++i;
    const int nl = wid - p.nstart[i];
    const float* wr = p.w[i] + (size_t)nl * 256;
    const float* gr = p.g[i];
    const float* br = p.bt[i];
    float s = 0.f, t = 0.f;
#pragma unroll
    for (int x = 0; x < 4; ++x) {
        const float wv = wr[lane * 4 + x];
        s += gr[lane * 4 + x] * wv;
        t += br[lane * 4 + x] * wv;
    }
#pragma unroll
    for (int o = 32; o; o >>= 1) {
        s += __shfl_xor(s, o);
        t += __shfl_xor(t, o);
    }
    if (!lane) { G[wid] = s; Bv[wid] = t; }
}

// ---------------------------------------------------------------------------
// gather_stats: window-partition [4,256,128,128] f32 -> raw bf16 window
// layout [1024*64,256] + per-token LN stats (mean, rstd).
// ---------------------------------------------------------------------------
__global__ __launch_bounds__(256)
void gather_stats_kernel(const float* __restrict__ X, u16* __restrict__ raw,
                         float* __restrict__ SS) {
    __shared__ __align__(16) u16 win[128][264];  // [w2*64 + y*8 + x][c]
    const int tid = threadIdx.x;
    const int blk2 = blockIdx.x;  // 0..511
    const int b = blk2 >> 7, hb = (blk2 >> 3) & 15, wp = blk2 & 7;
#pragma unroll
    for (int it = 0; it < 8; ++it) {
        const int id = it * 256 + tid;
        const int c = id & 255, y = id >> 8;
        const size_t off =
            (((size_t)(b * 256 + c) * 128) + hb * 8 + y) * 128 + wp * 16;
        f32x4 v0 = *(const f32x4*)(X + off);
        f32x4 v1 = *(const f32x4*)(X + off + 4);
        f32x4 v2 = *(const f32x4*)(X + off + 8);
        f32x4 v3 = *(const f32x4*)(X + off + 12);
#pragma unroll
        for (int x = 0; x < 4; ++x) {
            win[y * 8 + x][c] = f2b(v0[x]);
            win[y * 8 + 4 + x][c] = f2b(v1[x]);
            win[64 + y * 8 + x][c] = f2b(v2[x]);
            win[64 + y * 8 + 4 + x][c] = f2b(v3[x]);
        }
    }
    __syncthreads();
    const size_t btok = (size_t)((b * 16 + hb) * 16 + wp * 2) * 64;
    {
        const int tok = tid >> 1, half = tid & 1;
        float s = 0.f, s2 = 0.f;
#pragma unroll
        for (int i = 0; i < 16; ++i) {
            u32x4 rv = *(const u32x4*)&win[tok][half * 128 + i * 8];
            const u16* pv = (const u16*)&rv;
#pragma unroll
            for (int x = 0; x < 8; ++x) {
                float v = b2f(pv[x]);
                s += v;
                s2 += v * v;
            }
        }
        s += __shfl_xor(s, 1);
        s2 += __shfl_xor(s2, 1);
        const float mean = s * (1.f / 256.f);
        const float var = s2 * (1.f / 256.f) - mean * mean;
        if (!half) {
            SS[(btok + tok) * 2] = mean;
            SS[(btok + tok) * 2 + 1] = rsqrtf(var + 1e-5f);
        }
    }
    const size_t base = btok * 256;
#pragma unroll
    for (int it = 0; it < 16; ++it) {
        const int e8 = it * 256 + tid;
        const int tok = e8 >> 5, c0 = (e8 & 31) * 8;
        *(u32x4*)(raw + base + (size_t)e8 * 8) = *(const u32x4*)&win[tok][c0];
    }
}

// ---------------------------------------------------------------------------
// stats: per-token LN stats of [65536,256] bf16. One wave per token.
// ---------------------------------------------------------------------------
__global__ __launch_bounds__(256)
void stats_kernel(const u16* __restrict__ X, float* __restrict__ SS) {
    const int wave = threadIdx.x >> 6, lane = threadIdx.x & 63;
    const size_t tok = (size_t)blockIdx.x * 4 + wave;
    u32x2 v = *(const u32x2*)(X + tok * 256 + lane * 4);
    float f0 = b2f((u16)(v[0] & 0xffff)), f1 = b2f((u16)(v[0] >> 16));
    float f2v = b2f((u16)(v[1] & 0xffff)), f3 = b2f((u16)(v[1] >> 16));
    float s = f0 + f1 + f2v + f3;
    float s2 = f0 * f0 + f1 * f1 + f2v * f2v + f3 * f3;
#pragma unroll
    for (int off = 32; off; off >>= 1) {
        s += __shfl_xor(s, off);
        s2 += __shfl_xor(s2, off);
    }
    if (!lane) {
        const float mean = s * (1.f / 256.f);
        const float var = s2 * (1.f / 256.f) - mean * mean;
        SS[tok * 2] = mean;
        SS[tok * 2 + 1] = rsqrtf(var + 1e-5f);
    }
}

// ---------------------------------------------------------------------------
// GEMM v9: C[M,N] = A'[M,K] @ W[N,K]^T + bias. Tile 128x64, 512 thr
// (8 waves, 32x32 quadrants; wr=w>>1 over 4 row-bands, wc=w&1). BK=64
// dbuf: LDS = 2x(16K A + 8K B) = 48 KB -> 3 blocks/CU = 24 waves/CU.
// Stage = 3 instr/wave (2 A + 1 B); counted vmcnt(3), final vmcnt(0);
// hard barriers (fenced both sides). XCD decode: strip-blocks of an
// A-tile co-XCD'd. XOR-swizzled LDS both sides (rule #21).
// LNE=1: pre-folded W; LN correction in epilogue from stats[].
// RES: 0=none, 1=+bf16 windowed residual. EPI: 0=none, 1=GELU(exact).
// ---------------------------------------------------------------------------
template <int K, int N, int LNE, int RES, int EPI>
__global__ __launch_bounds__(512)
void gemm_kernel(const u16* __restrict__ A, const u16* __restrict__ Wt,
                 const float* __restrict__ bias, const float* __restrict__ stats,
                 const float* __restrict__ Gv, const float* __restrict__ Bv,
                 const u16* __restrict__ resw, u16* __restrict__ Cout) {
    constexpr int S = N / 64;    // N-strips
    constexpr int NPH = K / 64;  // phases (4 or 8)
    __shared__ __align__(16) u16 As[2][128 * 64];
    __shared__ __align__(16) u16 Bs[2][64 * 64];
    const int tid = threadIdx.x;
    const int lane = tid & 63, w = tid >> 6;   // 8 waves
    const int cl = lane & 15, g = lane >> 4;
    const int wr = w >> 1, wc = w & 1;
    const int bid = blockIdx.x;
    const int xcd = bid & 7, rest = bid >> 3;
    const int strip = rest % S, mseq = rest / S;
    const int m0 = (xcd * 64 + mseq) * 128;  // M-tile (512 total)
    const int n0 = strip * 64;
    const int rowg = lane >> 3;   // row within staged 8-row group
    const int sch = lane & 7;     // 16B chunk within 128B row
    f32x4 acc[2][2] = {};

    auto stage = [&](int c) {
        const int buf = c & 1;
#pragma unroll
        for (int it = 0; it < 2; ++it) {      // A: 16 rows per wave
            const int rp = w * 16 + it * 8;
            const int row = rp + rowg;
            const int ch = sch ^ (row & 7);   // pre-swizzled source chunk
            gload16(&A[(size_t)(m0 + row) * K + c * 64 + ch * 8],
                    &As[buf][rp * 64]);
        }
        {                                      // B: 8 rows per wave
            const int rp = w * 8;
            const int row = rp + rowg;
            const int ch = sch ^ (row & 7);
            gload16(&Wt[(size_t)(n0 + row) * K + c * 64 + ch * 8],
                    &Bs[buf][rp * 64]);
        }
    };
    stage(0);
    stage(1);
#pragma unroll
    for (int c = 0; c < NPH; ++c) {
        if (c + 1 < NPH)
            asm volatile("s_waitcnt vmcnt(3)" ::: "memory");  // stage(c) done
        else
            asm volatile("s_waitcnt vmcnt(0)" ::: "memory");
        hard_barrier();
        const u16* Ab = &As[c & 1][0];
        const u16* Bb = &Bs[c & 1][0];
#pragma unroll
        for (int ks = 0; ks < 2; ++ks) {
            const int J = ks * 4 + g;  // 16B chunk of row (0..7)
            bf16x8 af[2], bw[2];
#pragma unroll
            for (int i = 0; i < 2; ++i) {
                const int r = wr * 32 + i * 16 + cl;      // 0..127
                af[i] = *(const bf16x8*)(Ab + r * 64 + (J ^ (r & 7)) * 8);
            }
#pragma unroll
            for (int j = 0; j < 2; ++j) {
                const int r = wc * 32 + j * 16 + cl;      // 0..63
                bw[j] = *(const bf16x8*)(Bb + r * 64 + (J ^ (r & 7)) * 8);
            }
#pragma unroll
            for (int i = 0; i < 2; ++i)
#pragma unroll
                for (int j = 0; j < 2; ++j)
                    acc[i][j] = __builtin_amdgcn_mfma_f32_16x16x32_bf16(
                        af[i], bw[j], acc[i][j], 0, 0, 0);
        }
        asm volatile("s_waitcnt lgkmcnt(0)" ::: "memory");
        hard_barrier();
        if (c + 2 < NPH) stage(c + 2);
    }
    // ---- epilogue: acc -> LDS (reuse As, 128x72 = 18.4KB) -> 16B stores ----
    u16 (*Cs)[72] = (u16(*)[72])&As[0][0];
#pragma unroll
    for (int i = 0; i < 2; ++i)
#pragma unroll
        for (int j = 0; j < 2; ++j)
#pragma unroll
            for (int rr = 0; rr < 4; ++rr)
                Cs[wr * 32 + i * 16 + g * 4 + rr][wc * 32 + j * 16 + cl] =
                    f2b(acc[i][j][rr]);
    __syncthreads();
#pragma unroll
    for (int it = 0; it < 2; ++it) {
        const int idx = it * 512 + tid;
        const int row = idx >> 3, ch = idx & 7;
        const int grow = m0 + row, gcol = n0 + ch * 8;
        u32x4 cv = *(const u32x4*)&Cs[row][ch * 8];
        const u16* pc = (const u16*)&cv;
        f32x4 b0 = *(const f32x4*)&bias[gcol];
        f32x4 b1 = *(const f32x4*)&bias[gcol + 4];
        float v[8];
        if constexpr (LNE) {
            const float mean = stats[2 * (size_t)grow];
            const float rstd = stats[2 * (size_t)grow + 1];
            const float mr = mean * rstd;
            f32x4 G0 = *(const f32x4*)&Gv[gcol];
            f32x4 G1 = *(const f32x4*)&Gv[gcol + 4];
            f32x4 B0 = *(const f32x4*)&Bv[gcol];
            f32x4 B1 = *(const f32x4*)&Bv[gcol + 4];
#pragma unroll
            for (int x = 0; x < 4; ++x) {
                v[x] = rstd * b2f(pc[x]) - mr * G0[x] + B0[x] + b0[x];
                v[4 + x] = rstd * b2f(pc[4 + x]) - mr * G1[x] + B1[x] + b1[x];
            }
        } else {
#pragma unroll
            for (int x = 0; x < 4; ++x) {
                v[x] = b2f(pc[x]) + b0[x];
                v[4 + x] = b2f(pc[4 + x]) + b1[x];
            }
        }
        if constexpr (RES == 1) {
            u32x4 rv = *(const u32x4*)&resw[(size_t)grow * N + gcol];
            const u16* pr = (const u16*)&rv;
#pragma unroll
            for (int x = 0; x < 8; ++x) v[x] += b2f(pr[x]);
        }
        if constexpr (EPI == 1)
#pragma unroll
            for (int x = 0; x < 8; ++x)
                v[x] = 0.5f * v[x] * (1.f + erff(v[x] * 0.70710678118654752f));
        u32x4 ov;
#pragma unroll
        for (int x = 0; x < 4; ++x)
            ov[x] = (u32)f2b(v[2 * x]) | ((u32)f2b(v[2 * x + 1]) << 16);
        *(u32x4*)&Cout[(size_t)grow * N + gcol] = ov;
    }
}

// ---------------------------------------------------------------------------
// MFMA attention. One wave per (window, head). Grid 2048 x 256thr (4 waves).
// ---------------------------------------------------------------------------
__global__ __launch_bounds__(256)
void attn_mfma_kernel(const u16* __restrict__ Q, const u16* __restrict__ KV,
                      const float* __restrict__ rpb, u16* __restrict__ O) {
    __shared__ __align__(16) u16 Pq[4][64][72];
    __shared__ __align__(16) u16 Vt[4][32][72];
    __shared__ float rb[4][228];
    const int w = threadIdx.x >> 6, lane = threadIdx.x & 63;
    const int gw = blockIdx.x * 4 + w;
    const int win = gw >> 3, h = gw & 7;
    const int c = lane & 15, g = lane >> 4;
    for (int i = lane; i < 225; i += 64) rb[w][i] = rpb[i * 8 + h];
    {
        const u16* Vrow = KV + ((size_t)(win * 64 + lane)) * 512 + 256 + h * 32;
        u32x4 vv[4];
#pragma unroll
        for (int ch = 0; ch < 4; ++ch) vv[ch] = *(const u32x4*)(Vrow + ch * 8);
        const u16* pv = (const u16*)vv;
#pragma unroll
        for (int d = 0; d < 32; ++d) Vt[w][d][lane] = pv[d];
    }
    const u16* Qb = Q + ((size_t)win * 64 + c) * 256 + h * 32 + g * 8;
    const u16* Kb = KV + ((size_t)win * 64 + c) * 512 + h * 32 + g * 8;
    bf16x8 qf[4], kf[4];
#pragma unroll
    for (int t = 0; t < 4; ++t) {
        qf[t] = *(const bf16x8*)(Qb + (size_t)t * 16 * 256);
        kf[t] = *(const bf16x8*)(Kb + (size_t)t * 16 * 512);
    }
    f32x4 st[4][4];
#pragma unroll
    for (int kb = 0; kb < 4; ++kb)
#pragma unroll
        for (int qb = 0; qb < 4; ++qb) {
            f32x4 z = {0.f, 0.f, 0.f, 0.f};
            st[kb][qb] = __builtin_amdgcn_mfma_f32_16x16x32_bf16(kf[kb], qf[qb], z, 0, 0, 0);
        }
    __syncthreads();
    const float scale = 0.17677669529663687f;
    const int qy2 = c >> 3, qx = c & 7;
#pragma unroll
    for (int qb = 0; qb < 4; ++qb) {
        float sv[16];
#pragma unroll
        for (int kb = 0; kb < 4; ++kb)
#pragma unroll
            for (int r = 0; r < 4; ++r) {
                const int k = kb * 16 + 4 * g + r;
                const int dy = (qb * 2 + qy2) - (k >> 3) + 7;
                const int dx = qx - (k & 7) + 7;
                sv[kb * 4 + r] = st[kb][qb][r] * scale + rb[w][dy * 15 + dx];
            }
        float mx = sv[0];
#pragma unroll
        for (int j = 1; j < 16; ++j) mx = fmaxf(mx, sv[j]);
        mx = fmaxf(mx, __shfl_xor(mx, 16));
        mx = fmaxf(mx, __shfl_xor(mx, 32));
        float sum = 0.f;
#pragma unroll
        for (int j = 0; j < 16; ++j) {
            sv[j] = __expf(sv[j] - mx);
            sum += sv[j];
        }
        sum += __shfl_xor(sum, 16);
        sum += __shfl_xor(sum, 32);
        const float inv = 1.f / sum;
#pragma unroll
        for (int kb = 0; kb < 4; ++kb) {
            u32x2 pk;
            pk[0] = (u32)f2b(sv[kb * 4 + 0] * inv) | ((u32)f2b(sv[kb * 4 + 1] * inv) << 16);
            pk[1] = (u32)f2b(sv[kb * 4 + 2] * inv) | ((u32)f2b(sv[kb * 4 + 3] * inv) << 16);
            *(u32x2*)&Pq[w][qb * 16 + c][kb * 16 + 4 * g] = pk;
        }
    }
    __syncthreads();
    f32x4 ot[4][2] = {};
#pragma unroll
    for (int ks = 0; ks < 2; ++ks) {
        bf16x8 bfr[2];
#pragma unroll
        for (int db = 0; db < 2; ++db)
            bfr[db] = *(const bf16x8*)&Vt[w][db * 16 + c][ks * 32 + g * 8];
#pragma unroll
        for (int qb = 0; qb < 4; ++qb) {
            bf16x8 af = *(const bf16x8*)&Pq[w][qb * 16 + c][ks * 32 + g * 8];
#pragma unroll
            for (int db = 0; db < 2; ++db)
                ot[qb][db] = __builtin_amdgcn_mfma_f32_16x16x32_bf16(af, bfr[db], ot[qb][db], 0, 0, 0);
        }
    }
    u16* Ob = O + ((size_t)win * 64) * 256 + h * 32;
#pragma unroll
    for (int qb = 0; qb < 4; ++qb)
#pragma unroll
        for (int db = 0; db < 2; ++db)
#pragma unroll
            for (int r = 0; r < 4; ++r)
                Ob[(size_t)(qb * 16 + 4 * g + r) * 256 + db * 16 + c] = f2b(ot[qb][db][r]);
}

// ---------------------------------------------------------------------------
// scatter v2: window layout [1024*64,256] bf16 -> [4,256,128,128] f32.
// ---------------------------------------------------------------------------
__global__ __launch_bounds__(256)
void scatter_kernel(const u16* __restrict__ Wn, float* __restrict__ out) {
    __shared__ __align__(16) u16 win[128][264];
    const int tid = threadIdx.x;
    const int blk2 = blockIdx.x;  // 0..511
    const int b = blk2 >> 7, hb = (blk2 >> 3) & 15, wp = blk2 & 7;
    const size_t base = (size_t)((b * 16 + hb) * 16 + wp * 2) * 64 * 256;
#pragma unroll
    for (int it = 0; it < 16; ++it) {
        const int e8 = it * 256 + tid;
        const int tok = e8 >> 5, c0 = (e8 & 31) * 8;
        *(u32x4*)&win[tok][c0] = *(const u32x4*)(Wn + base + (size_t)e8 * 8);
    }
    __syncthreads();
#pragma unroll
    for (int it = 0; it < 8; ++it) {
        const int id = it * 256 + tid;
        const int c = id & 255, y = id >> 8;
        f32x4 o0, o1, o2, o3;
#pragma unroll
        for (int x = 0; x < 4; ++x) {
            o0[x] = b2f(win[y * 8 + x][c]);
            o1[x] = b2f(win[y * 8 + 4 + x][c]);
            o2[x] = b2f(win[64 + y * 8 + x][c]);
            o3[x] = b2f(win[64 + y * 8 + 4 + x][c]);
        }
        const size_t oo =
            (((size_t)(b * 256 + c) * 128) + hb * 8 + y) * 128 + wp * 16;
        *(f32x4*)(out + oo) = o0;
        *(f32x4*)(out + oo + 4) = o1;
        *(f32x4*)(out + oo + 8) = o2;
        *(f32x4*)(out + oo + 12) = o3;
    }
}

// ---------------------------------------------------------------------------
extern "C" void kernel_launch(void* const* d_in, const int* in_sizes, int n_in,
                              void* d_out, int out_size, void* d_ws,
                              size_t ws_size, hipStream_t stream) {
    const float* spatial = (const float*)d_in[0];
    const float* freq    = (const float*)d_in[1];
    const float* s_qw  = (const float*)d_in[2];
    const float* s_qb  = (const float*)d_in[3];
    const float* s_kvw = (const float*)d_in[4];
    const float* s_kvb = (const float*)d_in[5];
    const float* s_rpb = (const float*)d_in[6];
    const float* s_pw  = (const float*)d_in[7];
    const float* s_pb  = (const float*)d_in[8];
    const float* f_qw  = (const float*)d_in[9];
    const float* f_qb  = (const float*)d_in[10];
    const float* f_kvw = (const float*)d_in[11];
    const float* f_kvb = (const float*)d_in[12];
    const float* f_rpb = (const float*)d_in[13];
    const float* f_pw  = (const float*)d_in[14];
    const float* f_pb  = (const float*)d_in[15];
    const float* ns1_g = (const float*)d_in[16];
    const float* ns1_b = (const float*)d_in[17];
    const float* nfs_g = (const float*)d_in[18];
    const float* nfs_b = (const float*)d_in[19];
    const float* ns2_g = (const float*)d_in[20];
    const float* ns2_b = (const float*)d_in[21];
    const float* nf1_g = (const float*)d_in[22];
    const float* nf1_b = (const float*)d_in[23];
    const float* nsf_g = (const float*)d_in[24];
    const float* nsf_b = (const float*)d_in[25];
    const float* nf2_g = (const float*)d_in[26];
    const float* nf2_b = (const float*)d_in[27];
    const float* ffns_w1 = (const float*)d_in[28];
    const float* ffns_b1 = (const float*)d_in[29];
    const float* ffns_w2 = (const float*)d_in[30];
    const float* ffns_b2 = (const float*)d_in[31];
    const float* ffnf_w1 = (const float*)d_in[32];
    const float* ffnf_b1 = (const float*)d_in[33];
    const float* ffnf_w2 = (const float*)d_in[34];
    const float* ffnf_b2 = (const float*)d_in[35];

    float* out = (float*)d_out;
    char* ob = (char*)d_out;
    char* ws = (char*)d_ws;
    const size_t MB32 = (size_t)32 << 20;
    u16* U0  = (u16*)ob;               // 32 MiB (attn out)
    u16* U1  = (u16*)(ob + MB32);      // 32 MiB (q / s1)
    u16* U23 = (u16*)(ob + 2 * MB32);  // 64 MiB (kv / hid)
    u16* W0  = (u16*)ws;               // 32 MiB (s2, then f2)
    u16* W1  = (u16*)(ws + MB32);      // 32 MiB (f1)
    u16* WB  = (u16*)(ws + 2 * MB32);  // 2 MiB bf16 weights
    u16* R0  = (u16*)(ws + 2 * MB32 + (2 << 20));         // raw spatial win
    u16* R1  = (u16*)(ws + 2 * MB32 + (2 << 20) + MB32);  // raw freq win
    char* SSB = ws + 2 * MB32 + (2 << 20) + 2 * MB32;     // stats area
    float* SS0 = (float*)SSB;                  // spatial stats (512 KB)
    float* SS1 = (float*)(SSB + (512 << 10));  // freq stats
    float* SS2 = (float*)(SSB + (1024 << 10)); // s1 stats
    float* SS3 = (float*)(SSB + (1536 << 10)); // s2 stats
    float* SS4 = (float*)(SSB + (2048 << 10)); // f1 stats
    float* Gv  = (float*)(SSB + (2560 << 10)); // 2560 f32
    float* Bv  = Gv + 2560;

    // unit layout (64Ki elems each), per wconv startmap 0xECB9864310:
    // 0:s_qw  1-2:s_kvw  3:s_pw  4-5:ffns_w1  6-7:ffns_w2
    // 8:f_qw  9-10:f_kvw 11:f_pw 12-13:ffnf_w1 14-15:ffnf_w2
    const u16* w_sq  = WB;
    const u16* w_skv = WB + 1 * 65536;
    const u16* w_sp  = WB + 3 * 65536;
    const u16* w_sw1 = WB + 4 * 65536;
    const u16* w_sw2 = WB + 6 * 65536;
    const u16* w_fq  = WB + 8 * 65536;
    const u16* w_fkv = WB + 9 * 65536;
    const u16* w_fp  = WB + 11 * 65536;
    const u16* w_fw1 = WB + 12 * 65536;
    const u16* w_fw2 = WB + 14 * 65536;

    WPack wp;
    wp.s[0] = s_qw;    wp.gn[0] = ns1_g;
    wp.s[1] = s_kvw;   wp.gn[1] = nfs_g;
    wp.s[2] = s_pw;    wp.gn[2] = nullptr;
    wp.s[3] = ffns_w1; wp.gn[3] = ns2_g;
    wp.s[4] = ffns_w2; wp.gn[4] = nullptr;
    wp.s[5] = f_qw;    wp.gn[5] = nf1_g;
    wp.s[6] = f_kvw;   wp.gn[6] = nsf_g;
    wp.s[7] = f_pw;    wp.gn[7] = nullptr;
    wp.s[8] = ffnf_w1; wp.gn[8] = nf2_g;
    wp.s[9] = ffnf_w2; wp.gn[9] = nullptr;

    GBPack gp;
    gp.w[0] = s_qw;    gp.g[0] = ns1_g; gp.bt[0] = ns1_b;
    gp.w[1] = s_kvw;   gp.g[1] = nfs_g; gp.bt[1] = nfs_b;
    gp.w[2] = ffns_w1; gp.g[2] = ns2_g; gp.bt[2] = ns2_b;
    gp.w[3] = f_qw;    gp.g[3] = nf1_g; gp.bt[3] = nf1_b;
    gp.w[4] = f_kvw;   gp.g[4] = nsf_g; gp.bt[4] = nsf_b;
    gp.w[5] = ffnf_w1; gp.g[5] = nf2_g; gp.bt[5] = nf2_b;
    gp.nstart[0] = 0;    gp.nstart[1] = 256;  gp.nstart[2] = 768;
    gp.nstart[3] = 1280; gp.nstart[4] = 1536; gp.nstart[5] = 2048;
    gp.nstart[6] = 2560;
    const float* G_sq  = Gv + 0;    const float* B_sq  = Bv + 0;
    const float* G_skv = Gv + 256;  const float* B_skv = Bv + 256;
    const float* G_sw1 = Gv + 768;  const float* B_sw1 = Bv + 768;
    const float* G_fq  = Gv + 1280; const float* B_fq  = Bv + 1280;
    const float* G_fkv = Gv + 1536; const float* B_fkv = Bv + 1536;
    const float* G_fw1 = Gv + 2048; const float* B_fw1 = Bv + 2048;

    const dim3 B(256);
    const dim3 GB2(512);  // gemm block
    wconv_kernel<<<1024, B, 0, stream>>>(wp, WB);
    gb_kernel<<<640, B, 0, stream>>>(gp, Gv, Bv);
    gather_stats_kernel<<<512, B, 0, stream>>>(spatial, R0, SS0);
    gather_stats_kernel<<<512, B, 0, stream>>>(freq, R1, SS1);
    // --- direction 1: spatial queries attend frequency kv ---
    gemm_kernel<256, 512, 1, 0, 0><<<4096, GB2, 0, stream>>>(
        R1, w_skv, s_kvb, SS1, G_skv, B_skv, nullptr, U23);   // kv
    gemm_kernel<256, 256, 1, 0, 0><<<2048, GB2, 0, stream>>>(
        R0, w_sq, s_qb, SS0, G_sq, B_sq, nullptr, U1);        // q
    attn_mfma_kernel<<<2048, B, 0, stream>>>(U1, U23, s_rpb, U0);
    gemm_kernel<256, 256, 0, 1, 0><<<2048, GB2, 0, stream>>>(
        U0, w_sp, s_pb, nullptr, nullptr, nullptr, R0, U1);   // s1
    stats_kernel<<<16384, B, 0, stream>>>(U1, SS2);
    gemm_kernel<256, 512, 1, 0, 1><<<4096, GB2, 0, stream>>>(
        U1, w_sw1, ffns_b1, SS2, G_sw1, B_sw1, nullptr, U23); // hid (GELU)
    gemm_kernel<512, 256, 0, 1, 0><<<2048, GB2, 0, stream>>>(
        U23, w_sw2, ffns_b2, nullptr, nullptr, nullptr, U1, W0);  // s2
    stats_kernel<<<16384, B, 0, stream>>>(W0, SS3);
    // --- direction 2: frequency queries attend updated spatial kv ---
    gemm_kernel<256, 512, 1, 0, 0><<<4096, GB2, 0, stream>>>(
        W0, w_fkv, f_kvb, SS3, G_fkv, B_fkv, nullptr, U23);   // kv2
    gemm_kernel<256, 256, 1, 0, 0><<<2048, GB2, 0, stream>>>(
        R1, w_fq, f_qb, SS1, G_fq, B_fq, nullptr, U1);        // q2
    attn_mfma_kernel<<<2048, B, 0, stream>>>(U1, U23, f_rpb, U0);
    gemm_kernel<256, 256, 0, 1, 0><<<2048, GB2, 0, stream>>>(
        U0, w_fp, f_pb, nullptr, nullptr, nullptr, R1, W1);   // f1
    stats_kernel<<<16384, B, 0, stream>>>(W1, SS4);
    gemm_kernel<256, 512, 1, 0, 1><<<4096, GB2, 0, stream>>>(
        W1, w_fw1, ffnf_b1, SS4, G_fw1, B_fw1, nullptr, U23); // hid2 (GELU)
    scatter_kernel<<<512, B, 0, stream>>>(W0, out);           // spatial_out
    gemm_kernel<512, 256, 0, 1, 0><<<2048, GB2, 0, stream>>>(
        U23, w_fw2, ffnf_b2, nullptr, nullptr, nullptr, W1, W0);  // f2
    scatter_kernel<<<512, B, 0, stream>>>(W0, out + 16777216);    // freq_out
}